// Round 1
// baseline (1234.735 us; speedup 1.0000x reference)
//
#include <hip/hip_runtime.h>
#include <math.h>

#define BB 4
#define NN 4096
#define FEAT 64
#define HID 128
#define KNN 16
#define GW 256
#define GH 256
#define GS 258
#define CIN 66
#define NC 8
#define CHUNK (NN / NC)

// ---------------- grid build ----------------
__global__ void k_grid_init(int* grid) {
    int i = blockIdx.x * 256 + threadIdx.x;
    if (i < BB * GS * GS) grid[i] = -1;
}

__global__ void k_scatter(const float* __restrict__ xyzp, int* __restrict__ grid, int* __restrict__ cxy) {
    int i = blockIdx.x * 256 + threadIdx.x;
    if (i >= BB * NN) return;
    int b = i / NN, n = i % NN;
    float x = xyzp[(size_t)i * 4 + 0], y = xyzp[(size_t)i * 4 + 1];
    int cx = __float2int_rn(x * 256.0f);
    int cy = __float2int_rn(y * 256.0f);
    cxy[i] = cx | (cy << 8);
    grid[b * GS * GS + (cy + 1) * GS + (cx + 1)] = n;
}

// ---------------- exact KNN: integer d2, tie-break lower index ----------------
__global__ __launch_bounds__(256) void k_knn_part(const int* __restrict__ cxy, unsigned* __restrict__ part) {
    int bid = blockIdx.x;
    int ch = bid % NC; bid /= NC;
    int qb = bid % (NN / 256);
    int b = bid / (NN / 256);
    int n = qb * 256 + threadIdx.x;
    __shared__ int sc[CHUNK];
    for (int t = threadIdx.x; t < CHUNK; t += 256) sc[t] = cxy[b * NN + ch * CHUNK + t];
    __syncthreads();
    int me = cxy[b * NN + n];
    int mx = me & 255, my = (me >> 8) & 255;
    unsigned a[KNN];
#pragma unroll
    for (int j = 0; j < KNN; j++) a[j] = 0xFFFFFFFFu;
    for (int t = 0; t < CHUNK; ++t) {
        int c = sc[t];
        int dx = mx - (c & 255), dy = my - ((c >> 8) & 255);
        unsigned d2 = (unsigned)(dx * dx + dy * dy);
        unsigned key = (d2 << 12) | (unsigned)(ch * CHUNK + t);
        if (key < a[KNN - 1]) {
#pragma unroll
            for (int j = KNN - 1; j >= 1; --j) {
                unsigned prev = a[j - 1];
                a[j] = (prev > key) ? prev : ((a[j] > key) ? key : a[j]);
            }
            a[0] = a[0] < key ? a[0] : key;
        }
    }
    unsigned* dst = part + ((size_t)(b * NN + n) * NC + ch) * KNN;
#pragma unroll
    for (int j = 0; j < KNN; j++) dst[j] = a[j];
}

__global__ __launch_bounds__(64) void k_knn_merge(const unsigned* __restrict__ part, int* __restrict__ idxo) {
    int q = blockIdx.x * 64 + threadIdx.x;
    if (q >= BB * NN) return;
    unsigned a[KNN];
#pragma unroll
    for (int j = 0; j < KNN; j++) a[j] = 0xFFFFFFFFu;
    for (int ch = 0; ch < NC; ++ch) {
#pragma unroll
        for (int j = 0; j < KNN; j++) {
            unsigned key = part[((size_t)q * NC + ch) * KNN + j];
            if (key < a[KNN - 1]) {
#pragma unroll
                for (int t = KNN - 1; t >= 1; --t) {
                    unsigned prev = a[t - 1];
                    a[t] = (prev > key) ? prev : ((a[t] > key) ? key : a[t]);
                }
                a[0] = a[0] < key ? a[0] : key;
            }
        }
    }
#pragma unroll
    for (int j = 0; j < KNN; j++) idxo[(size_t)q * KNN + j] = (int)(a[j] & 4095u);
}

// ---------------- sp = LayerNorm(concat(clip(p'), -clip(p'), features)) ----------------
__global__ __launch_bounds__(256) void k_sp(const float* __restrict__ xyzp, const float* __restrict__ feat,
                                            const float* __restrict__ ln_g, const float* __restrict__ ln_b,
                                            float* __restrict__ sp) {
    int i = blockIdx.x * 256 + threadIdx.x;
    if (i >= BB * NN) return;
    float v[CIN];
    float p = xyzp[(size_t)i * 4 + 3];
    float pn = (p - 0.5f) * 2.0f;
    v[0] = fminf(fmaxf(pn, 0.0f), 1.0f);
    v[1] = -fminf(fmaxf(pn, -1.0f), 0.0f);
    const float4* f4 = (const float4*)(feat + (size_t)i * FEAT);
#pragma unroll
    for (int j = 0; j < FEAT / 4; j++) {
        float4 t = f4[j];
        v[2 + 4 * j] = t.x; v[3 + 4 * j] = t.y; v[4 + 4 * j] = t.z; v[5 + 4 * j] = t.w;
    }
    float s = 0.0f;
#pragma unroll
    for (int j = 0; j < CIN; j++) s += v[j];
    float mu = s / (float)CIN;
    float vs = 0.0f;
#pragma unroll
    for (int j = 0; j < CIN; j++) { float d = v[j] - mu; vs += d * d; }
    float inv = 1.0f / sqrtf(vs / (float)CIN + 1e-5f);
    float* o = sp + (size_t)i * CIN;
#pragma unroll
    for (int j = 0; j < CIN; j++) o[j] = (v[j] - mu) * inv * ln_g[j] + ln_b[j];
}

// ---------------- conv1: h1 = einsum(gather9(sp), W1) + b1 ----------------
__global__ __launch_bounds__(256) void k_conv1(const int* __restrict__ grid, const int* __restrict__ cxy,
                                               const float* __restrict__ sp, const float* __restrict__ W1,
                                               const float* __restrict__ b1, float* __restrict__ h1) {
    __shared__ int sj[9][64];
    __shared__ __align__(16) float As[64][68];
    __shared__ float Ws[CIN * 128];
    int row0 = blockIdx.x * 64;
    int b = row0 / NN;
    int tid = threadIdx.x;
    for (int e = tid; e < 9 * 64; e += 256) {
        int k = e / 64, p = e % 64;
        int me = cxy[row0 + p];
        int cx = me & 255, cy = (me >> 8) & 255;
        int dy = k / 3 - 1, dx = k % 3 - 1;
        sj[k][p] = grid[b * GS * GS + (cy + 1 + dy) * GS + (cx + 1 + dx)];
    }
    float acc[32];
#pragma unroll
    for (int i = 0; i < 32; i++) acc[i] = 0.0f;
    int d = tid & 127, pg = tid >> 7;
    for (int k = 0; k < 9; ++k) {
        __syncthreads();
        for (int e = tid; e < 64 * CIN; e += 256) {
            int p = e / CIN, c = e % CIN;
            int j = sj[k][p];
            As[p][c] = (j >= 0) ? sp[((size_t)b * NN + j) * CIN + c] : 0.0f;
        }
        for (int e = tid; e < CIN * 128; e += 256) Ws[e] = W1[k * CIN * 128 + e];
        __syncthreads();
        for (int c2 = 0; c2 < CIN / 2; ++c2) {
            int c = c2 * 2;
            float w0 = Ws[c * 128 + d], w1 = Ws[(c + 1) * 128 + d];
#pragma unroll
            for (int i = 0; i < 32; ++i) {
                float2 f = *(const float2*)&As[pg * 32 + i][c];
                acc[i] += f.x * w0 + f.y * w1;
            }
        }
    }
    float bb = b1[d];
#pragma unroll
    for (int i = 0; i < 32; i++) h1[(size_t)(row0 + pg * 32 + i) * 128 + d] = acc[i] + bb;
}

// ---------------- conv2: h2 = einsum(gather9(h1), W2) -> q,k,v ----------------
__global__ __launch_bounds__(256) void k_conv2(const int* __restrict__ grid, const int* __restrict__ cxy,
                                               const float* __restrict__ h1, const float* __restrict__ W2,
                                               float* __restrict__ qg, float* __restrict__ kg, float* __restrict__ vg) {
    __shared__ int sj[9][64];
    __shared__ __align__(16) float As[64][64];
    __shared__ float Ws[64 * 128];
    int bid = blockIdx.x;
    int nb = bid % 3;
    int mb = bid / 3;
    int n0 = nb * 128;
    int row0 = mb * 64;
    int b = row0 / NN;
    int tid = threadIdx.x;
    for (int e = tid; e < 9 * 64; e += 256) {
        int k = e / 64, p = e % 64;
        int me = cxy[row0 + p];
        int cx = me & 255, cy = (me >> 8) & 255;
        int dy = k / 3 - 1, dx = k % 3 - 1;
        sj[k][p] = grid[b * GS * GS + (cy + 1 + dy) * GS + (cx + 1 + dx)];
    }
    float acc[32];
#pragma unroll
    for (int i = 0; i < 32; i++) acc[i] = 0.0f;
    int d = tid & 127, pg = tid >> 7;
    for (int kc = 0; kc < 18; ++kc) {
        int k = kc >> 1, c0 = (kc & 1) * 64;
        __syncthreads();
        for (int e = tid; e < 64 * 64; e += 256) {
            int p = e >> 6, c = e & 63;
            int j = sj[k][p];
            As[p][c] = (j >= 0) ? h1[((size_t)b * NN + j) * 128 + c0 + c] : 0.0f;
        }
        for (int e = tid; e < 64 * 128; e += 256) {
            int c = e >> 7, dd = e & 127;
            Ws[e] = W2[(size_t)(k * 128 + c0 + c) * 384 + n0 + dd];
        }
        __syncthreads();
        for (int c4 = 0; c4 < 16; ++c4) {
            int c = c4 * 4;
            float w0 = Ws[c * 128 + d], w1 = Ws[(c + 1) * 128 + d];
            float w2 = Ws[(c + 2) * 128 + d], w3 = Ws[(c + 3) * 128 + d];
#pragma unroll
            for (int i = 0; i < 32; ++i) {
                float4 f = *(const float4*)&As[pg * 32 + i][c];
                acc[i] += f.x * w0 + f.y * w1 + f.z * w2 + f.w * w3;
            }
        }
    }
    int col = n0 + d;
    int s = col % 3, dd = col / 3;
    float* dst = (s == 0) ? qg : (s == 1) ? kg : vg;
#pragma unroll
    for (int i = 0; i < 32; i++) dst[(size_t)(row0 + pg * 32 + i) * 128 + dd] = acc[i];
}

// ---------------- fused attention: pe-MLP, q-k+pe, 2x(128x128), softmax_K, sum(v+pe) ----------------
__global__ __launch_bounds__(256) void k_attn(const float* __restrict__ xyzp, const int* __restrict__ idx,
                                              const float* __restrict__ qg, const float* __restrict__ kg,
                                              const float* __restrict__ vg,
                                              const float* __restrict__ pe_w1, const float* __restrict__ pe_b1,
                                              const float* __restrict__ pe_w2, const float* __restrict__ pe_b2,
                                              const float* __restrict__ at_w1, const float* __restrict__ at_b1,
                                              const float* __restrict__ at_w2, const float* __restrict__ at_b2,
                                              float* __restrict__ res1) {
    __shared__ __align__(16) float s_pe[2][16][128];
    __shared__ __align__(16) float s_x[2][16][128];
    __shared__ __align__(16) float s_y[2][16][128];
    __shared__ int s_j[2][16];
    __shared__ float s_rel[2][16][4];
    int tid = threadIdx.x;
    int p = tid >> 7, d = tid & 127;
    int R = blockIdx.x * 2 + p;
    int b = R / NN;
    size_t base = (size_t)b * NN;
    if (d < 16) {
        int j = idx[(size_t)R * 16 + d];
        s_j[p][d] = j;
        s_rel[p][d][0] = xyzp[(size_t)R * 4 + 0] - xyzp[(base + j) * 4 + 0];
        s_rel[p][d][1] = xyzp[(size_t)R * 4 + 1] - xyzp[(base + j) * 4 + 1];
        s_rel[p][d][2] = xyzp[(size_t)R * 4 + 3] - xyzp[(base + j) * 4 + 3];
    }
    __syncthreads();
    // PE1: s_x = relu(rel @ pe_w1 + pe_b1)
    {
        float w0 = pe_w1[d], w1 = pe_w1[128 + d], w2 = pe_w1[256 + d], bb = pe_b1[d];
#pragma unroll
        for (int k = 0; k < 16; k++) {
            float v = s_rel[p][k][0] * w0 + s_rel[p][k][1] * w1 + s_rel[p][k][2] * w2 + bb;
            s_x[p][k][d] = fmaxf(v, 0.0f);
        }
    }
    __syncthreads();
    // PE2: s_pe = s_x @ pe_w2 + pe_b2
    {
        float acc[16];
#pragma unroll
        for (int k = 0; k < 16; k++) acc[k] = 0.0f;
        for (int c4 = 0; c4 < 32; c4++) {
            int c = c4 * 4;
            float w0 = pe_w2[c * 128 + d], w1 = pe_w2[(c + 1) * 128 + d];
            float w2 = pe_w2[(c + 2) * 128 + d], w3 = pe_w2[(c + 3) * 128 + d];
#pragma unroll
            for (int k = 0; k < 16; k++) {
                float4 f = *(const float4*)&s_x[p][k][c];
                acc[k] += f.x * w0 + f.y * w1 + f.z * w2 + f.w * w3;
            }
        }
        float bb = pe_b2[d];
#pragma unroll
        for (int k = 0; k < 16; k++) s_pe[p][k][d] = acc[k] + bb;
    }
    __syncthreads();
    // T: s_y = q - k_j + pe
    {
        float qv = qg[(size_t)R * 128 + d];
#pragma unroll
        for (int k = 0; k < 16; k++) {
            int j = s_j[p][k];
            s_y[p][k][d] = qv - kg[(base + j) * 128 + d] + s_pe[p][k][d];
        }
    }
    __syncthreads();
    // A1: s_x = relu(s_y @ at_w1 + at_b1)
    {
        float acc[16];
#pragma unroll
        for (int k = 0; k < 16; k++) acc[k] = 0.0f;
        for (int c4 = 0; c4 < 32; c4++) {
            int c = c4 * 4;
            float w0 = at_w1[c * 128 + d], w1 = at_w1[(c + 1) * 128 + d];
            float w2 = at_w1[(c + 2) * 128 + d], w3 = at_w1[(c + 3) * 128 + d];
#pragma unroll
            for (int k = 0; k < 16; k++) {
                float4 f = *(const float4*)&s_y[p][k][c];
                acc[k] += f.x * w0 + f.y * w1 + f.z * w2 + f.w * w3;
            }
        }
        float bb = at_b1[d];
#pragma unroll
        for (int k = 0; k < 16; k++) s_x[p][k][d] = fmaxf(acc[k] + bb, 0.0f);
    }
    __syncthreads();
    // A2: s_y = s_x @ at_w2 + at_b2
    {
        float acc[16];
#pragma unroll
        for (int k = 0; k < 16; k++) acc[k] = 0.0f;
        for (int c4 = 0; c4 < 32; c4++) {
            int c = c4 * 4;
            float w0 = at_w2[c * 128 + d], w1 = at_w2[(c + 1) * 128 + d];
            float w2 = at_w2[(c + 2) * 128 + d], w3 = at_w2[(c + 3) * 128 + d];
#pragma unroll
            for (int k = 0; k < 16; k++) {
                float4 f = *(const float4*)&s_x[p][k][c];
                acc[k] += f.x * w0 + f.y * w1 + f.z * w2 + f.w * w3;
            }
        }
        float bb = at_b2[d];
#pragma unroll
        for (int k = 0; k < 16; k++) s_y[p][k][d] = acc[k] + bb;
    }
    __syncthreads();
    // softmax over K (per channel) + weighted sum of (v + pe)
    {
        const float scale = 0.08838834764831845f;  // 1/sqrt(128)
        float vals[16];
        float m = -1e30f;
#pragma unroll
        for (int k = 0; k < 16; k++) { vals[k] = s_y[p][k][d] * scale; m = fmaxf(m, vals[k]); }
        float ssum = 0.0f;
#pragma unroll
        for (int k = 0; k < 16; k++) { vals[k] = expf(vals[k] - m); ssum += vals[k]; }
        float o = 0.0f;
#pragma unroll
        for (int k = 0; k < 16; k++) {
            int j = s_j[p][k];
            o += vals[k] * (vg[(base + j) * 128 + d] + s_pe[p][k][d]);
        }
        res1[(size_t)R * 128 + d] = o / ssum;
    }
}

// ---------------- final head: ag + MLP with exact gelu, residuals ----------------
__global__ __launch_bounds__(256) void k_head(const float* __restrict__ res1, const float* __restrict__ feat,
                                              const float* __restrict__ ag_w, const float* __restrict__ ag_b,
                                              const float* __restrict__ mlp_w1, const float* __restrict__ mlp_b1,
                                              const float* __restrict__ mlp_w2, const float* __restrict__ mlp_b2,
                                              float* __restrict__ out) {
    __shared__ __align__(16) float rs[64][128];  // res1 rows; reused as hidden after gelu
    __shared__ __align__(16) float r1s[64][64];
    int tid = threadIdx.x;
    int i0 = blockIdx.x * 64;
    for (int e = tid; e < 64 * 128; e += 256) rs[e >> 7][e & 127] = res1[(size_t)i0 * 128 + e];
    __syncthreads();
    {  // phase1: r1 = rs @ ag_w + ag_b + feat
        int d = tid & 63, rg = tid >> 6;
        float acc[16];
#pragma unroll
        for (int i = 0; i < 16; i++) acc[i] = 0.0f;
        for (int c4 = 0; c4 < 32; ++c4) {
            int c = c4 * 4;
            float w0 = ag_w[c * 64 + d], w1 = ag_w[(c + 1) * 64 + d];
            float w2 = ag_w[(c + 2) * 64 + d], w3 = ag_w[(c + 3) * 64 + d];
#pragma unroll
            for (int i = 0; i < 16; i++) {
                float4 f = *(const float4*)&rs[rg * 16 + i][c];
                acc[i] += f.x * w0 + f.y * w1 + f.z * w2 + f.w * w3;
            }
        }
        float bb = ag_b[d];
#pragma unroll
        for (int i = 0; i < 16; i++) {
            int pp = rg * 16 + i;
            r1s[pp][d] = acc[i] + bb + feat[(size_t)(i0 + pp) * 64 + d];
        }
    }
    __syncthreads();
    {  // phase2: rs = gelu(r1s @ mlp_w1 + mlp_b1)
        int d = tid & 127, rg = tid >> 7;
        float acc[32];
#pragma unroll
        for (int i = 0; i < 32; i++) acc[i] = 0.0f;
        for (int c4 = 0; c4 < 16; ++c4) {
            int c = c4 * 4;
            float w0 = mlp_w1[c * 128 + d], w1 = mlp_w1[(c + 1) * 128 + d];
            float w2 = mlp_w1[(c + 2) * 128 + d], w3 = mlp_w1[(c + 3) * 128 + d];
#pragma unroll
            for (int i = 0; i < 32; i++) {
                float4 f = *(const float4*)&r1s[rg * 32 + i][c];
                acc[i] += f.x * w0 + f.y * w1 + f.z * w2 + f.w * w3;
            }
        }
        float bb = mlp_b1[d];
#pragma unroll
        for (int i = 0; i < 32; i++) {
            float x = acc[i] + bb;
            rs[rg * 32 + i][d] = 0.5f * x * (1.0f + erff(x * 0.70710678118654752f));
        }
    }
    __syncthreads();
    {  // phase3: out = rs @ mlp_w2 + mlp_b2 + feat
        int d = tid & 63, rg = tid >> 6;
        float acc[16];
#pragma unroll
        for (int i = 0; i < 16; i++) acc[i] = 0.0f;
        for (int c4 = 0; c4 < 32; ++c4) {
            int c = c4 * 4;
            float w0 = mlp_w2[c * 64 + d], w1 = mlp_w2[(c + 1) * 64 + d];
            float w2 = mlp_w2[(c + 2) * 64 + d], w3 = mlp_w2[(c + 3) * 64 + d];
#pragma unroll
            for (int i = 0; i < 16; i++) {
                float4 f = *(const float4*)&rs[rg * 16 + i][c];
                acc[i] += f.x * w0 + f.y * w1 + f.z * w2 + f.w * w3;
            }
        }
        float bb = mlp_b2[d];
#pragma unroll
        for (int i = 0; i < 16; i++) {
            int pp = rg * 16 + i;
            out[(size_t)(i0 + pp) * 64 + d] = acc[i] + bb + feat[(size_t)(i0 + pp) * 64 + d];
        }
    }
}

extern "C" void kernel_launch(void* const* d_in, const int* in_sizes, int n_in,
                              void* d_out, int out_size, void* d_ws, size_t ws_size,
                              hipStream_t stream) {
    const float* xyzp = (const float*)d_in[0];
    const float* features = (const float*)d_in[1];
    const float* ln_g = (const float*)d_in[2];
    const float* ln_b = (const float*)d_in[3];
    const float* W1 = (const float*)d_in[4];
    const float* b1 = (const float*)d_in[5];
    const float* W2 = (const float*)d_in[6];
    const float* pe_w1 = (const float*)d_in[7];
    const float* pe_b1 = (const float*)d_in[8];
    const float* pe_w2 = (const float*)d_in[9];
    const float* pe_b2 = (const float*)d_in[10];
    const float* at_w1 = (const float*)d_in[11];
    const float* at_b1 = (const float*)d_in[12];
    const float* at_w2 = (const float*)d_in[13];
    const float* at_b2 = (const float*)d_in[14];
    const float* ag_w = (const float*)d_in[15];
    const float* ag_b = (const float*)d_in[16];
    const float* mlp_w1 = (const float*)d_in[17];
    const float* mlp_b1 = (const float*)d_in[18];
    const float* mlp_w2 = (const float*)d_in[19];
    const float* mlp_b2 = (const float*)d_in[20];
    float* out = (float*)d_out;

    char* w = (char*)d_ws;
    auto alloc = [&](size_t bytes) { char* pp = w; w += (bytes + 255) & ~(size_t)255; return pp; };
    int* grid = (int*)alloc((size_t)BB * GS * GS * 4);
    int* cxy = (int*)alloc((size_t)BB * NN * 4);
    unsigned* part = (unsigned*)alloc((size_t)BB * NN * NC * KNN * 4);
    int* idxb = (int*)alloc((size_t)BB * NN * KNN * 4);
    float* sp = (float*)alloc((size_t)BB * NN * CIN * 4);
    float* h1 = (float*)alloc((size_t)BB * NN * HID * 4);
    float* qg = (float*)alloc((size_t)BB * NN * HID * 4);
    float* kg = (float*)alloc((size_t)BB * NN * HID * 4);
    float* vg = (float*)alloc((size_t)BB * NN * HID * 4);
    float* res1 = (float*)alloc((size_t)BB * NN * HID * 4);

    k_grid_init<<<(BB * GS * GS + 255) / 256, 256, 0, stream>>>(grid);
    k_scatter<<<(BB * NN + 255) / 256, 256, 0, stream>>>(xyzp, grid, cxy);
    k_knn_part<<<BB * (NN / 256) * NC, 256, 0, stream>>>(cxy, part);
    k_knn_merge<<<BB * NN / 64, 64, 0, stream>>>(part, idxb);
    k_sp<<<(BB * NN + 255) / 256, 256, 0, stream>>>(xyzp, features, ln_g, ln_b, sp);
    k_conv1<<<BB * NN / 64, 256, 0, stream>>>(grid, cxy, sp, W1, b1, h1);
    k_conv2<<<(BB * NN / 64) * 3, 256, 0, stream>>>(grid, cxy, h1, W2, qg, kg, vg);
    k_attn<<<BB * NN / 2, 256, 0, stream>>>(xyzp, idxb, qg, kg, vg, pe_w1, pe_b1, pe_w2, pe_b2,
                                            at_w1, at_b1, at_w2, at_b2, res1);
    k_head<<<BB * NN / 64, 256, 0, stream>>>(res1, features, ag_w, ag_b, mlp_w1, mlp_b1, mlp_w2, mlp_b2, out);
}

// Round 2
// 518.273 us; speedup vs baseline: 2.3824x; 2.3824x over previous
//
#include <hip/hip_runtime.h>
#include <math.h>

#define BB 4
#define NN 4096
#define FEAT 64
#define HID 128
#define KNN 16
#define GS 258
#define CIN 66
#define NC 8
#define CHUNK (NN / NC)

typedef __attribute__((ext_vector_type(8))) short bf16x8;
typedef __attribute__((ext_vector_type(4))) float f32x4;
#define MFMA_B16(a, b, c) __builtin_amdgcn_mfma_f32_16x16x32_bf16(a, b, c, 0, 0, 0)

__device__ __forceinline__ short f2b(float f) {
    unsigned u = __builtin_bit_cast(unsigned, f);
    u = (u + 0x7FFFu + ((u >> 16) & 1u)) >> 16;
    return (short)u;
}
__device__ __forceinline__ float b2f(short s) {
    return __builtin_bit_cast(float, ((unsigned)(unsigned short)s) << 16);
}

// ---------------- grid build ----------------
__global__ void k_grid_init(int* grid) {
    int i = blockIdx.x * 256 + threadIdx.x;
    if (i < BB * GS * GS) grid[i] = -1;
}

__global__ void k_scatter(const float* __restrict__ xyzp, int* __restrict__ grid, int* __restrict__ cxy) {
    int i = blockIdx.x * 256 + threadIdx.x;
    if (i >= BB * NN) return;
    int b = i / NN, n = i % NN;
    float x = xyzp[(size_t)i * 4 + 0], y = xyzp[(size_t)i * 4 + 1];
    int cx = __float2int_rn(x * 256.0f);
    int cy = __float2int_rn(y * 256.0f);
    cxy[i] = cx | (cy << 8);
    grid[b * GS * GS + (cy + 1) * GS + (cx + 1)] = n;
}

// ---------------- exact KNN (integer d2, tie-break lower index) ----------------
__global__ __launch_bounds__(256) void k_knn_part(const int* __restrict__ cxy, unsigned* __restrict__ part) {
    int bid = blockIdx.x;
    int ch = bid % NC; bid /= NC;
    int qb = bid % (NN / 256);
    int b = bid / (NN / 256);
    int n = qb * 256 + threadIdx.x;
    __shared__ int sc[CHUNK];
    for (int t = threadIdx.x; t < CHUNK; t += 256) sc[t] = cxy[b * NN + ch * CHUNK + t];
    __syncthreads();
    int me = cxy[b * NN + n];
    int mx = me & 255, my = (me >> 8) & 255;
    unsigned a[KNN];
#pragma unroll
    for (int j = 0; j < KNN; j++) a[j] = 0xFFFFFFFFu;
    for (int t = 0; t < CHUNK; ++t) {
        int c = sc[t];
        int dx = mx - (c & 255), dy = my - ((c >> 8) & 255);
        unsigned d2 = (unsigned)(dx * dx + dy * dy);
        unsigned key = (d2 << 12) | (unsigned)(ch * CHUNK + t);
        if (key < a[KNN - 1]) {
#pragma unroll
            for (int j = KNN - 1; j >= 1; --j) {
                unsigned prev = a[j - 1];
                a[j] = (prev > key) ? prev : ((a[j] > key) ? key : a[j]);
            }
            a[0] = a[0] < key ? a[0] : key;
        }
    }
    unsigned* dst = part + ((size_t)(b * NN + n) * NC + ch) * KNN;
#pragma unroll
    for (int j = 0; j < KNN; j++) dst[j] = a[j];
}

__global__ __launch_bounds__(64) void k_knn_merge(const unsigned* __restrict__ part, int* __restrict__ idxo) {
    int q = blockIdx.x * 64 + threadIdx.x;
    if (q >= BB * NN) return;
    unsigned a[KNN];
#pragma unroll
    for (int j = 0; j < KNN; j++) a[j] = 0xFFFFFFFFu;
    for (int ch = 0; ch < NC; ++ch) {
#pragma unroll
        for (int j = 0; j < KNN; j++) {
            unsigned key = part[((size_t)q * NC + ch) * KNN + j];
            if (key < a[KNN - 1]) {
#pragma unroll
                for (int t = KNN - 1; t >= 1; --t) {
                    unsigned prev = a[t - 1];
                    a[t] = (prev > key) ? prev : ((a[t] > key) ? key : a[t]);
                }
                a[0] = a[0] < key ? a[0] : key;
            }
        }
    }
#pragma unroll
    for (int j = 0; j < KNN; j++) idxo[(size_t)q * KNN + j] = (int)(a[j] & 4095u);
}

// ---------------- weight pre-pack into bf16 MFMA B-fragments ----------------
#define PK128_SZ (4 * 8 * 512)
#define PKW1_SZ (9 * 3 * 8 * 512)
#define PKW2_SZ (9 * 4 * 24 * 512)

__global__ __launch_bounds__(256) void k_pack(const float* __restrict__ pe_w2, const float* __restrict__ at_w1,
                                              const float* __restrict__ at_w2, const float* __restrict__ W1,
                                              const float* __restrict__ W2,
                                              short* __restrict__ pk_pe2, short* __restrict__ pk_a1,
                                              short* __restrict__ pk_a2, short* __restrict__ pk_w1,
                                              short* __restrict__ pk_w2) {
    int i = blockIdx.x * 256 + threadIdx.x;
    if (i < 3 * PK128_SZ) {
        int seg = i / PK128_SZ, r = i % PK128_SZ;
        int f = r / 512, q = r % 512;
        int lane = q / 8, j = q % 8;
        int kt = f / 8, nt = f % 8;
        int k = kt * 32 + (lane >> 4) * 8 + j, n = nt * 16 + (lane & 15);
        const float* W = (seg == 0) ? pe_w2 : (seg == 1) ? at_w1 : at_w2;
        short* dst = (seg == 0) ? pk_pe2 : (seg == 1) ? pk_a1 : pk_a2;
        dst[r] = f2b(W[k * 128 + n]);
        return;
    }
    i -= 3 * PK128_SZ;
    if (i < PKW1_SZ) {
        int f = i / 512, q = i % 512;
        int lane = q / 8, j = q % 8;
        int tap = f / 24, rem = f % 24;
        int kt = rem / 8, nt = rem % 8;
        int k = kt * 32 + (lane >> 4) * 8 + j, n = nt * 16 + (lane & 15);
        pk_w1[i] = (k < CIN) ? f2b(W1[(tap * CIN + k) * 128 + n]) : (short)0;
        return;
    }
    i -= PKW1_SZ;
    if (i < PKW2_SZ) {
        int f = i / 512, q = i % 512;
        int lane = q / 8, j = q % 8;
        int tap = f / 96, rem = f % 96;
        int kt = rem / 24, nt = rem % 24;
        int k = kt * 32 + (lane >> 4) * 8 + j, n = nt * 16 + (lane & 15);
        pk_w2[i] = f2b(W2[((size_t)(tap * 128 + k)) * 384 + n]);
    }
}

// ---------------- sp = LayerNorm(...) -> bf16, padded to 96 cols ----------------
__global__ __launch_bounds__(256) void k_sp(const float* __restrict__ xyzp, const float* __restrict__ feat,
                                            const float* __restrict__ ln_g, const float* __restrict__ ln_b,
                                            short* __restrict__ sp_bf) {
    int i = blockIdx.x * 256 + threadIdx.x;
    if (i >= BB * NN) return;
    float v[CIN];
    float p = xyzp[(size_t)i * 4 + 3];
    float pn = (p - 0.5f) * 2.0f;
    v[0] = fminf(fmaxf(pn, 0.0f), 1.0f);
    v[1] = -fminf(fmaxf(pn, -1.0f), 0.0f);
    const float4* f4 = (const float4*)(feat + (size_t)i * FEAT);
#pragma unroll
    for (int j = 0; j < FEAT / 4; j++) {
        float4 t = f4[j];
        v[2 + 4 * j] = t.x; v[3 + 4 * j] = t.y; v[4 + 4 * j] = t.z; v[5 + 4 * j] = t.w;
    }
    float s = 0.0f;
#pragma unroll
    for (int j = 0; j < CIN; j++) s += v[j];
    float mu = s / (float)CIN;
    float vs = 0.0f;
#pragma unroll
    for (int j = 0; j < CIN; j++) { float d = v[j] - mu; vs += d * d; }
    float inv = 1.0f / sqrtf(vs / (float)CIN + 1e-5f);
    short* o = sp_bf + (size_t)i * 96;
#pragma unroll
    for (int j = 0; j < CIN; j++) o[j] = f2b((v[j] - mu) * inv * ln_g[j] + ln_b[j]);
#pragma unroll
    for (int j = CIN; j < 96; j++) o[j] = 0;
}

// ---------------- conv1 (MFMA): h1 = einsum(gather9(sp), W1) + b1 -> bf16 ----------------
__global__ __launch_bounds__(256) void k_conv1(const int* __restrict__ grid, const int* __restrict__ cxy,
                                               const short* __restrict__ sp_bf, const float* __restrict__ b1,
                                               const short* __restrict__ pk_w1, short* __restrict__ h1_bf) {
    __shared__ int sj[9][32];
    __shared__ __align__(16) char s_A[32 * 256];
    int row0 = blockIdx.x * 32;
    int b = row0 / NN;
    int tid = threadIdx.x;
    for (int e = tid; e < 9 * 32; e += 256) {
        int k = e / 32, p = e % 32;
        int me = cxy[row0 + p];
        int cx = me & 255, cy = (me >> 8) & 255;
        sj[k][p] = grid[b * GS * GS + (cy + k / 3) * GS + (cx + k % 3)];
    }
    int w = tid >> 6, l = tid & 63;
    f32x4 acc[2][2];
#pragma unroll
    for (int mt = 0; mt < 2; mt++)
#pragma unroll
        for (int nt = 0; nt < 2; nt++) acc[mt][nt] = (f32x4){0.f, 0.f, 0.f, 0.f};
    for (int tap = 0; tap < 9; ++tap) {
        __syncthreads();
        for (int e = tid; e < 384; e += 256) {
            int p = e / 12, ch = e % 12;
            int j = sj[tap][p];
            int4 val = {0, 0, 0, 0};
            if (j >= 0) val = *(const int4*)(sp_bf + ((size_t)(b * NN + j) * 96 + ch * 8));
            *(int4*)&s_A[p * 256 + ((ch * 16) ^ ((p & 7) << 4))] = val;
        }
        __syncthreads();
#pragma unroll
        for (int kt = 0; kt < 3; ++kt) {
            int r0a = (l & 15);
            bf16x8 a0 = *(const bf16x8*)&s_A[r0a * 256 + ((kt * 64 + (l >> 4) * 16) ^ ((r0a & 7) << 4))];
            int r1a = 16 + (l & 15);
            bf16x8 a1 = *(const bf16x8*)&s_A[r1a * 256 + ((kt * 64 + (l >> 4) * 16) ^ ((r1a & 7) << 4))];
#pragma unroll
            for (int nt = 0; nt < 2; ++nt) {
                bf16x8 bv = *(const bf16x8*)(pk_w1 + (size_t)(((tap * 3 + kt) * 8 + (w * 2 + nt)) * 64 + l) * 8);
                acc[0][nt] = MFMA_B16(a0, bv, acc[0][nt]);
                acc[1][nt] = MFMA_B16(a1, bv, acc[1][nt]);
            }
        }
    }
    int cl = l & 15;
#pragma unroll
    for (int nt = 0; nt < 2; ++nt) {
        int col = w * 32 + nt * 16 + cl;
        float bb = b1[col];
#pragma unroll
        for (int mt = 0; mt < 2; ++mt)
#pragma unroll
            for (int j = 0; j < 4; ++j) {
                int row = row0 + mt * 16 + (l >> 4) * 4 + j;
                h1_bf[(size_t)row * 128 + col] = f2b(acc[mt][nt][j] + bb);
            }
    }
}

// ---------------- conv2 (MFMA): h2 = einsum(gather9(h1), W2) -> q,k,v bf16 ----------------
__global__ __launch_bounds__(256) void k_conv2(const int* __restrict__ grid, const int* __restrict__ cxy,
                                               const short* __restrict__ h1_bf, const short* __restrict__ pk_w2,
                                               short* __restrict__ qg, short* __restrict__ kg, short* __restrict__ vg) {
    __shared__ int sj[9][32];
    __shared__ __align__(16) char s_A[32 * 256];
    int row0 = blockIdx.x * 32;
    int b = row0 / NN;
    int tid = threadIdx.x;
    for (int e = tid; e < 9 * 32; e += 256) {
        int k = e / 32, p = e % 32;
        int me = cxy[row0 + p];
        int cx = me & 255, cy = (me >> 8) & 255;
        sj[k][p] = grid[b * GS * GS + (cy + k / 3) * GS + (cx + k % 3)];
    }
    int w = tid >> 6, l = tid & 63;
    f32x4 acc[2][6];
#pragma unroll
    for (int mt = 0; mt < 2; mt++)
#pragma unroll
        for (int nt = 0; nt < 6; nt++) acc[mt][nt] = (f32x4){0.f, 0.f, 0.f, 0.f};
    for (int tap = 0; tap < 9; ++tap) {
        __syncthreads();
        for (int e = tid; e < 512; e += 256) {
            int p = e >> 4, ch = e & 15;
            int j = sj[tap][p];
            int4 val = {0, 0, 0, 0};
            if (j >= 0) val = *(const int4*)(h1_bf + ((size_t)(b * NN + j) * 128 + ch * 8));
            *(int4*)&s_A[p * 256 + ((ch * 16) ^ ((p & 7) << 4))] = val;
        }
        __syncthreads();
#pragma unroll
        for (int kt = 0; kt < 4; ++kt) {
            int r0a = (l & 15);
            bf16x8 a0 = *(const bf16x8*)&s_A[r0a * 256 + ((kt * 64 + (l >> 4) * 16) ^ ((r0a & 7) << 4))];
            int r1a = 16 + (l & 15);
            bf16x8 a1 = *(const bf16x8*)&s_A[r1a * 256 + ((kt * 64 + (l >> 4) * 16) ^ ((r1a & 7) << 4))];
#pragma unroll
            for (int nt = 0; nt < 6; ++nt) {
                bf16x8 bv = *(const bf16x8*)(pk_w2 + (size_t)(((tap * 4 + kt) * 24 + (w * 6 + nt)) * 64 + l) * 8);
                acc[0][nt] = MFMA_B16(a0, bv, acc[0][nt]);
                acc[1][nt] = MFMA_B16(a1, bv, acc[1][nt]);
            }
        }
    }
    int cl = l & 15;
#pragma unroll
    for (int nt = 0; nt < 6; ++nt) {
        int col = w * 96 + nt * 16 + cl;
        int s = col % 3, dd = col / 3;
        short* dst = (s == 0) ? qg : (s == 1) ? kg : vg;
#pragma unroll
        for (int mt = 0; mt < 2; ++mt)
#pragma unroll
            for (int j = 0; j < 4; ++j) {
                int row = row0 + mt * 16 + (l >> 4) * 4 + j;
                dst[(size_t)row * 128 + dd] = f2b(acc[mt][nt][j]);
            }
    }
}

// ---------------- fused attention (MFMA, barrier-free per-wave) ----------------
__global__ __launch_bounds__(256) void k_attn(const float* __restrict__ xyzp, const int* __restrict__ idx,
                                              const short* __restrict__ qg, const short* __restrict__ kg,
                                              const short* __restrict__ vg,
                                              const float* __restrict__ pe_w1, const float* __restrict__ pe_b1,
                                              const float* __restrict__ pe_b2, const float* __restrict__ at_b1,
                                              const float* __restrict__ at_b2,
                                              const short* __restrict__ pk_pe2, const short* __restrict__ pk_a1,
                                              const short* __restrict__ pk_a2, float* __restrict__ res1) {
    __shared__ __align__(16) char s_A[128 * 256];
    __shared__ int s_j[128];
    __shared__ float s_rel[128][3];
    int tid = threadIdx.x;
    int w = tid >> 6, l = tid & 63;
    int r0 = w * 32;
    int p0 = blockIdx.x * 8;

    if (l < 32) {
        int rr = r0 + l;
        int P = p0 + (rr >> 4);
        int base = (P >> 12) << 12;
        int j = idx[(size_t)P * 16 + (rr & 15)];
        int g = base + j;
        s_j[rr] = g;
        s_rel[rr][0] = xyzp[(size_t)P * 4 + 0] - xyzp[(size_t)g * 4 + 0];
        s_rel[rr][1] = xyzp[(size_t)P * 4 + 1] - xyzp[(size_t)g * 4 + 1];
        s_rel[rr][2] = xyzp[(size_t)P * 4 + 3] - xyzp[(size_t)g * 4 + 3];
    }
    // PE1: hidden = relu(rel @ pe_w1 + pe_b1) -> s_A (bf16, swizzled)
    {
        int c0 = 2 * l;
        float wa0 = pe_w1[c0], wa1 = pe_w1[c0 + 1];
        float wb0 = pe_w1[128 + c0], wb1 = pe_w1[129 + c0];
        float wc0 = pe_w1[256 + c0], wc1 = pe_w1[257 + c0];
        float ba0 = pe_b1[c0], ba1 = pe_b1[c0 + 1];
        for (int rr = r0; rr < r0 + 32; ++rr) {
            float rx = s_rel[rr][0], ry = s_rel[rr][1], rp = s_rel[rr][2];
            float h0 = fmaxf(rx * wa0 + ry * wb0 + rp * wc0 + ba0, 0.f);
            float h1v = fmaxf(rx * wa1 + ry * wb1 + rp * wc1 + ba1, 0.f);
            unsigned pk = (unsigned)(unsigned short)f2b(h0) | (((unsigned)(unsigned short)f2b(h1v)) << 16);
            *(unsigned*)&s_A[rr * 256 + ((c0 * 2) ^ ((rr & 7) << 4))] = pk;
        }
    }
    int cl = l & 15;
    f32x4 pe_[2][8];
    f32x4 acc[2][8];
#pragma unroll
    for (int mt = 0; mt < 2; mt++)
#pragma unroll
        for (int nt = 0; nt < 8; nt++) pe_[mt][nt] = (f32x4){0.f, 0.f, 0.f, 0.f};
    // PE2 GEMM
#pragma unroll
    for (int kt = 0; kt < 4; ++kt) {
        int ra = r0 + (l & 15);
        bf16x8 a0 = *(const bf16x8*)&s_A[ra * 256 + ((kt * 64 + (l >> 4) * 16) ^ ((ra & 7) << 4))];
        int rb = ra + 16;
        bf16x8 a1 = *(const bf16x8*)&s_A[rb * 256 + ((kt * 64 + (l >> 4) * 16) ^ ((rb & 7) << 4))];
#pragma unroll
        for (int nt = 0; nt < 8; ++nt) {
            bf16x8 bv = *(const bf16x8*)(pk_pe2 + (size_t)((kt * 8 + nt) * 64 + l) * 8);
            pe_[0][nt] = MFMA_B16(a0, bv, pe_[0][nt]);
            pe_[1][nt] = MFMA_B16(a1, bv, pe_[1][nt]);
        }
    }
    // + pe_b2; build t = q - k + pe -> s_A
#pragma unroll
    for (int nt = 0; nt < 8; ++nt) {
        float b2v = pe_b2[nt * 16 + cl];
#pragma unroll
        for (int mt = 0; mt < 2; ++mt)
#pragma unroll
            for (int j = 0; j < 4; ++j) pe_[mt][nt][j] += b2v;
    }
#pragma unroll
    for (int mt = 0; mt < 2; ++mt) {
        int P = p0 + w * 2 + mt;
#pragma unroll
        for (int nt = 0; nt < 8; ++nt) {
            int col = nt * 16 + cl;
            float qv = b2f(qg[(size_t)P * 128 + col]);
#pragma unroll
            for (int j = 0; j < 4; ++j) {
                int rr = r0 + mt * 16 + (l >> 4) * 4 + j;
                int g = s_j[rr];
                float kv = b2f(kg[(size_t)g * 128 + col]);
                *(short*)&s_A[rr * 256 + ((col * 2) ^ ((rr & 7) << 4))] = f2b(qv - kv + pe_[mt][nt][j]);
            }
        }
    }
    // A1 GEMM
#pragma unroll
    for (int mt = 0; mt < 2; mt++)
#pragma unroll
        for (int nt = 0; nt < 8; nt++) acc[mt][nt] = (f32x4){0.f, 0.f, 0.f, 0.f};
#pragma unroll
    for (int kt = 0; kt < 4; ++kt) {
        int ra = r0 + (l & 15);
        bf16x8 a0 = *(const bf16x8*)&s_A[ra * 256 + ((kt * 64 + (l >> 4) * 16) ^ ((ra & 7) << 4))];
        int rb = ra + 16;
        bf16x8 a1 = *(const bf16x8*)&s_A[rb * 256 + ((kt * 64 + (l >> 4) * 16) ^ ((rb & 7) << 4))];
#pragma unroll
        for (int nt = 0; nt < 8; ++nt) {
            bf16x8 bv = *(const bf16x8*)(pk_a1 + (size_t)((kt * 8 + nt) * 64 + l) * 8);
            acc[0][nt] = MFMA_B16(a0, bv, acc[0][nt]);
            acc[1][nt] = MFMA_B16(a1, bv, acc[1][nt]);
        }
    }
    // relu(+at_b1) -> s_A
#pragma unroll
    for (int nt = 0; nt < 8; ++nt) {
        float bv = at_b1[nt * 16 + cl];
        int col = nt * 16 + cl;
#pragma unroll
        for (int mt = 0; mt < 2; ++mt)
#pragma unroll
            for (int j = 0; j < 4; ++j) {
                int rr = r0 + mt * 16 + (l >> 4) * 4 + j;
                *(short*)&s_A[rr * 256 + ((col * 2) ^ ((rr & 7) << 4))] = f2b(fmaxf(acc[mt][nt][j] + bv, 0.f));
            }
    }
    // A2 GEMM
#pragma unroll
    for (int mt = 0; mt < 2; mt++)
#pragma unroll
        for (int nt = 0; nt < 8; nt++) acc[mt][nt] = (f32x4){0.f, 0.f, 0.f, 0.f};
#pragma unroll
    for (int kt = 0; kt < 4; ++kt) {
        int ra = r0 + (l & 15);
        bf16x8 a0 = *(const bf16x8*)&s_A[ra * 256 + ((kt * 64 + (l >> 4) * 16) ^ ((ra & 7) << 4))];
        int rb = ra + 16;
        bf16x8 a1 = *(const bf16x8*)&s_A[rb * 256 + ((kt * 64 + (l >> 4) * 16) ^ ((rb & 7) << 4))];
#pragma unroll
        for (int nt = 0; nt < 8; ++nt) {
            bf16x8 bv = *(const bf16x8*)(pk_a2 + (size_t)((kt * 8 + nt) * 64 + l) * 8);
            acc[0][nt] = MFMA_B16(a0, bv, acc[0][nt]);
            acc[1][nt] = MFMA_B16(a1, bv, acc[1][nt]);
        }
    }
    // softmax over K (rows of each 16-tile) + weighted (v+pe) sum
    const float scale = 0.08838834764831845f;
#pragma unroll
    for (int mt = 0; mt < 2; ++mt) {
        int P = p0 + w * 2 + mt;
#pragma unroll
        for (int nt = 0; nt < 8; ++nt) {
            int col = nt * 16 + cl;
            float bv = at_b2[col];
            float vv[4];
#pragma unroll
            for (int j = 0; j < 4; ++j) vv[j] = (acc[mt][nt][j] + bv) * scale;
            float m = fmaxf(fmaxf(vv[0], vv[1]), fmaxf(vv[2], vv[3]));
            m = fmaxf(m, __shfl_xor(m, 16));
            m = fmaxf(m, __shfl_xor(m, 32));
            float ee[4], es = 0.f;
#pragma unroll
            for (int j = 0; j < 4; ++j) { ee[j] = __expf(vv[j] - m); es += ee[j]; }
            es += __shfl_xor(es, 16);
            es += __shfl_xor(es, 32);
            float o = 0.f;
#pragma unroll
            for (int j = 0; j < 4; ++j) {
                int rr = r0 + mt * 16 + (l >> 4) * 4 + j;
                int g = s_j[rr];
                float vvv = b2f(vg[(size_t)g * 128 + col]);
                o += ee[j] * (vvv + pe_[mt][nt][j]);
            }
            o += __shfl_xor(o, 16);
            o += __shfl_xor(o, 32);
            if (l < 16) res1[(size_t)P * 128 + col] = o / es;
        }
    }
}

// ---------------- final head (f32 VALU) ----------------
__global__ __launch_bounds__(256) void k_head(const float* __restrict__ res1, const float* __restrict__ feat,
                                              const float* __restrict__ ag_w, const float* __restrict__ ag_b,
                                              const float* __restrict__ mlp_w1, const float* __restrict__ mlp_b1,
                                              const float* __restrict__ mlp_w2, const float* __restrict__ mlp_b2,
                                              float* __restrict__ out) {
    __shared__ __align__(16) float rs[64][128];
    __shared__ __align__(16) float r1s[64][64];
    int tid = threadIdx.x;
    int i0 = blockIdx.x * 64;
    for (int e = tid; e < 64 * 128; e += 256) rs[e >> 7][e & 127] = res1[(size_t)i0 * 128 + e];
    __syncthreads();
    {
        int d = tid & 63, rg = tid >> 6;
        float acc[16];
#pragma unroll
        for (int i = 0; i < 16; i++) acc[i] = 0.0f;
        for (int c4 = 0; c4 < 32; ++c4) {
            int c = c4 * 4;
            float w0 = ag_w[c * 64 + d], w1 = ag_w[(c + 1) * 64 + d];
            float w2 = ag_w[(c + 2) * 64 + d], w3 = ag_w[(c + 3) * 64 + d];
#pragma unroll
            for (int i = 0; i < 16; i++) {
                float4 f = *(const float4*)&rs[rg * 16 + i][c];
                acc[i] += f.x * w0 + f.y * w1 + f.z * w2 + f.w * w3;
            }
        }
        float bb = ag_b[d];
#pragma unroll
        for (int i = 0; i < 16; i++) {
            int pp = rg * 16 + i;
            r1s[pp][d] = acc[i] + bb + feat[(size_t)(i0 + pp) * 64 + d];
        }
    }
    __syncthreads();
    {
        int d = tid & 127, rg = tid >> 7;
        float acc[32];
#pragma unroll
        for (int i = 0; i < 32; i++) acc[i] = 0.0f;
        for (int c4 = 0; c4 < 16; ++c4) {
            int c = c4 * 4;
            float w0 = mlp_w1[c * 128 + d], w1 = mlp_w1[(c + 1) * 128 + d];
            float w2 = mlp_w1[(c + 2) * 128 + d], w3 = mlp_w1[(c + 3) * 128 + d];
#pragma unroll
            for (int i = 0; i < 32; i++) {
                float4 f = *(const float4*)&r1s[rg * 32 + i][c];
                acc[i] += f.x * w0 + f.y * w1 + f.z * w2 + f.w * w3;
            }
        }
        float bb = mlp_b1[d];
#pragma unroll
        for (int i = 0; i < 32; i++) {
            float x = acc[i] + bb;
            rs[rg * 32 + i][d] = 0.5f * x * (1.0f + erff(x * 0.70710678118654752f));
        }
    }
    __syncthreads();
    {
        int d = tid & 63, rg = tid >> 6;
        float acc[16];
#pragma unroll
        for (int i = 0; i < 16; i++) acc[i] = 0.0f;
        for (int c4 = 0; c4 < 32; ++c4) {
            int c = c4 * 4;
            float w0 = mlp_w2[c * 64 + d], w1 = mlp_w2[(c + 1) * 64 + d];
            float w2 = mlp_w2[(c + 2) * 64 + d], w3 = mlp_w2[(c + 3) * 64 + d];
#pragma unroll
            for (int i = 0; i < 16; i++) {
                float4 f = *(const float4*)&rs[rg * 16 + i][c];
                acc[i] += f.x * w0 + f.y * w1 + f.z * w2 + f.w * w3;
            }
        }
        float bb = mlp_b2[d];
#pragma unroll
        for (int i = 0; i < 16; i++) {
            int pp = rg * 16 + i;
            out[(size_t)(i0 + pp) * 64 + d] = acc[i] + bb + feat[(size_t)(i0 + pp) * 64 + d];
        }
    }
}

extern "C" void kernel_launch(void* const* d_in, const int* in_sizes, int n_in,
                              void* d_out, int out_size, void* d_ws, size_t ws_size,
                              hipStream_t stream) {
    const float* xyzp = (const float*)d_in[0];
    const float* features = (const float*)d_in[1];
    const float* ln_g = (const float*)d_in[2];
    const float* ln_b = (const float*)d_in[3];
    const float* W1 = (const float*)d_in[4];
    const float* b1 = (const float*)d_in[5];
    const float* W2 = (const float*)d_in[6];
    const float* pe_w1 = (const float*)d_in[7];
    const float* pe_b1 = (const float*)d_in[8];
    const float* pe_w2 = (const float*)d_in[9];
    const float* pe_b2 = (const float*)d_in[10];
    const float* at_w1 = (const float*)d_in[11];
    const float* at_b1 = (const float*)d_in[12];
    const float* at_w2 = (const float*)d_in[13];
    const float* at_b2 = (const float*)d_in[14];
    const float* ag_w = (const float*)d_in[15];
    const float* ag_b = (const float*)d_in[16];
    const float* mlp_w1 = (const float*)d_in[17];
    const float* mlp_b1 = (const float*)d_in[18];
    const float* mlp_w2 = (const float*)d_in[19];
    const float* mlp_b2 = (const float*)d_in[20];
    float* out = (float*)d_out;

    char* w = (char*)d_ws;
    auto alloc = [&](size_t bytes) { char* pp = w; w += (bytes + 255) & ~(size_t)255; return pp; };
    int* grid = (int*)alloc((size_t)BB * GS * GS * 4);
    int* cxy = (int*)alloc((size_t)BB * NN * 4);
    unsigned* part = (unsigned*)alloc((size_t)BB * NN * NC * KNN * 4);
    int* idxb = (int*)alloc((size_t)BB * NN * KNN * 4);
    short* sp_bf = (short*)alloc((size_t)BB * NN * 96 * 2);
    short* h1_bf = (short*)alloc((size_t)BB * NN * HID * 2);
    short* qg = (short*)alloc((size_t)BB * NN * HID * 2);
    short* kg = (short*)alloc((size_t)BB * NN * HID * 2);
    short* vg = (short*)alloc((size_t)BB * NN * HID * 2);
    float* res1 = (float*)alloc((size_t)BB * NN * HID * 4);
    short* pk_pe2 = (short*)alloc((size_t)PK128_SZ * 2);
    short* pk_a1 = (short*)alloc((size_t)PK128_SZ * 2);
    short* pk_a2 = (short*)alloc((size_t)PK128_SZ * 2);
    short* pk_w1 = (short*)alloc((size_t)PKW1_SZ * 2);
    short* pk_w2 = (short*)alloc((size_t)PKW2_SZ * 2);

    k_grid_init<<<(BB * GS * GS + 255) / 256, 256, 0, stream>>>(grid);
    k_scatter<<<(BB * NN + 255) / 256, 256, 0, stream>>>(xyzp, grid, cxy);
    k_pack<<<(3 * PK128_SZ + PKW1_SZ + PKW2_SZ + 255) / 256, 256, 0, stream>>>(
        pe_w2, at_w1, at_w2, W1, W2, pk_pe2, pk_a1, pk_a2, pk_w1, pk_w2);
    k_knn_part<<<BB * (NN / 256) * NC, 256, 0, stream>>>(cxy, part);
    k_knn_merge<<<BB * NN / 64, 64, 0, stream>>>(part, idxb);
    k_sp<<<(BB * NN + 255) / 256, 256, 0, stream>>>(xyzp, features, ln_g, ln_b, sp_bf);
    k_conv1<<<BB * NN / 32, 256, 0, stream>>>(grid, cxy, sp_bf, b1, pk_w1, h1_bf);
    k_conv2<<<BB * NN / 32, 256, 0, stream>>>(grid, cxy, h1_bf, pk_w2, qg, kg, vg);
    k_attn<<<BB * NN / 8, 256, 0, stream>>>(xyzp, idxb, qg, kg, vg, pe_w1, pe_b1, pe_b2, at_b1, at_b2,
                                            pk_pe2, pk_a1, pk_a2, res1);
    k_head<<<BB * NN / 64, 256, 0, stream>>>(res1, features, ag_w, ag_b, mlp_w1, mlp_b1, mlp_w2, mlp_b2, out);
}

// Round 3
// 464.494 us; speedup vs baseline: 2.6582x; 1.1158x over previous
//
#include <hip/hip_runtime.h>
#include <math.h>

#define BB 4
#define NN 4096
#define FEAT 64
#define HID 128
#define KNN 16
#define GS 258
#define CIN 66
#define NC 8
#define CHUNK (NN / NC)

typedef __attribute__((ext_vector_type(8))) short bf16x8;
typedef __attribute__((ext_vector_type(4))) float f32x4;
#define MFMA_B16(a, b, c) __builtin_amdgcn_mfma_f32_16x16x32_bf16(a, b, c, 0, 0, 0)

__device__ __forceinline__ short f2b(float f) {
    unsigned u = __builtin_bit_cast(unsigned, f);
    u = (u + 0x7FFFu + ((u >> 16) & 1u)) >> 16;
    return (short)u;
}
__device__ __forceinline__ float b2f(short s) {
    return __builtin_bit_cast(float, ((unsigned)(unsigned short)s) << 16);
}
__device__ __forceinline__ void gload_lds16(const void* g, void* lds) {
    __builtin_amdgcn_global_load_lds((const __attribute__((address_space(1))) unsigned int*)g,
                                     (__attribute__((address_space(3))) unsigned int*)lds, 16, 0, 0);
}

// ---------------- grid build ----------------
__global__ void k_grid_init(int* grid) {
    int i = blockIdx.x * 256 + threadIdx.x;
    if (i < BB * GS * GS) grid[i] = -1;
}

__global__ void k_scatter(const float* __restrict__ xyzp, int* __restrict__ grid, int* __restrict__ cxy) {
    int i = blockIdx.x * 256 + threadIdx.x;
    if (i >= BB * NN) return;
    int b = i / NN, n = i % NN;
    float x = xyzp[(size_t)i * 4 + 0], y = xyzp[(size_t)i * 4 + 1];
    int cx = __float2int_rn(x * 256.0f);
    int cy = __float2int_rn(y * 256.0f);
    cxy[i] = cx | (cy << 8);
    grid[b * GS * GS + (cy + 1) * GS + (cx + 1)] = n;
}

// ---------------- exact KNN (integer d2, tie-break lower index) ----------------
__global__ __launch_bounds__(256) void k_knn_part(const int* __restrict__ cxy, unsigned* __restrict__ part) {
    int bid = blockIdx.x;
    int ch = bid % NC; bid /= NC;
    int qb = bid % (NN / 256);
    int b = bid / (NN / 256);
    int n = qb * 256 + threadIdx.x;
    __shared__ int sc[CHUNK];
    for (int t = threadIdx.x; t < CHUNK; t += 256) sc[t] = cxy[b * NN + ch * CHUNK + t];
    __syncthreads();
    int me = cxy[b * NN + n];
    int mx = me & 255, my = (me >> 8) & 255;
    unsigned a[KNN];
#pragma unroll
    for (int j = 0; j < KNN; j++) a[j] = 0xFFFFFFFFu;
    for (int t = 0; t < CHUNK; ++t) {
        int c = sc[t];
        int dx = mx - (c & 255), dy = my - ((c >> 8) & 255);
        unsigned d2 = (unsigned)(dx * dx + dy * dy);
        unsigned key = (d2 << 12) | (unsigned)(ch * CHUNK + t);
        if (key < a[KNN - 1]) {
#pragma unroll
            for (int j = KNN - 1; j >= 1; --j) {
                unsigned prev = a[j - 1];
                a[j] = (prev > key) ? prev : ((a[j] > key) ? key : a[j]);
            }
            a[0] = a[0] < key ? a[0] : key;
        }
    }
    unsigned* dst = part + ((size_t)(b * NN + n) * NC + ch) * KNN;
#pragma unroll
    for (int j = 0; j < KNN; j++) dst[j] = a[j];
}

__global__ __launch_bounds__(64) void k_knn_merge(const unsigned* __restrict__ part, int* __restrict__ idxo) {
    int q = blockIdx.x * 64 + threadIdx.x;
    if (q >= BB * NN) return;
    unsigned a[KNN];
#pragma unroll
    for (int j = 0; j < KNN; j++) a[j] = 0xFFFFFFFFu;
    for (int ch = 0; ch < NC; ++ch) {
#pragma unroll
        for (int j = 0; j < KNN; j++) {
            unsigned key = part[((size_t)q * NC + ch) * KNN + j];
            if (key < a[KNN - 1]) {
#pragma unroll
                for (int t = KNN - 1; t >= 1; --t) {
                    unsigned prev = a[t - 1];
                    a[t] = (prev > key) ? prev : ((a[t] > key) ? key : a[t]);
                }
                a[0] = a[0] < key ? a[0] : key;
            }
        }
    }
#pragma unroll
    for (int j = 0; j < KNN; j++) idxo[(size_t)q * KNN + j] = (int)(a[j] & 4095u);
}

// ---------------- weight pre-pack into bf16 MFMA B-fragments ----------------
#define PK128_SZ (4 * 8 * 512)
#define PKW1_SZ (9 * 3 * 8 * 512)
#define PKW2_SZ (9 * 4 * 24 * 512)

__global__ __launch_bounds__(256) void k_pack(const float* __restrict__ pe_w2, const float* __restrict__ at_w1,
                                              const float* __restrict__ at_w2, const float* __restrict__ W1,
                                              const float* __restrict__ W2,
                                              short* __restrict__ pk_pe2, short* __restrict__ pk_a1,
                                              short* __restrict__ pk_a2, short* __restrict__ pk_w1,
                                              short* __restrict__ pk_w2) {
    int i = blockIdx.x * 256 + threadIdx.x;
    if (i < 3 * PK128_SZ) {
        int seg = i / PK128_SZ, r = i % PK128_SZ;
        int f = r / 512, q = r % 512;
        int lane = q / 8, j = q % 8;
        int kt = f / 8, nt = f % 8;
        int k = kt * 32 + (lane >> 4) * 8 + j, n = nt * 16 + (lane & 15);
        const float* W = (seg == 0) ? pe_w2 : (seg == 1) ? at_w1 : at_w2;
        short* dst = (seg == 0) ? pk_pe2 : (seg == 1) ? pk_a1 : pk_a2;
        dst[r] = f2b(W[k * 128 + n]);
        return;
    }
    i -= 3 * PK128_SZ;
    if (i < PKW1_SZ) {
        int f = i / 512, q = i % 512;
        int lane = q / 8, j = q % 8;
        int tap = f / 24, rem = f % 24;
        int kt = rem / 8, nt = rem % 8;
        int k = kt * 32 + (lane >> 4) * 8 + j, n = nt * 16 + (lane & 15);
        pk_w1[i] = (k < CIN) ? f2b(W1[(tap * CIN + k) * 128 + n]) : (short)0;
        return;
    }
    i -= PKW1_SZ;
    if (i < PKW2_SZ) {
        int f = i / 512, q = i % 512;
        int lane = q / 8, j = q % 8;
        int tap = f / 96, rem = f % 96;
        int kt = rem / 24, nt = rem % 24;
        int k = kt * 32 + (lane >> 4) * 8 + j, n = nt * 16 + (lane & 15);
        pk_w2[i] = f2b(W2[((size_t)(tap * 128 + k)) * 384 + n]);
    }
}

// ---------------- sp = LayerNorm(...) -> bf16, padded to 96 cols ----------------
__global__ __launch_bounds__(256) void k_sp(const float* __restrict__ xyzp, const float* __restrict__ feat,
                                            const float* __restrict__ ln_g, const float* __restrict__ ln_b,
                                            short* __restrict__ sp_bf) {
    int i = blockIdx.x * 256 + threadIdx.x;
    if (i >= BB * NN) return;
    float v[CIN];
    float p = xyzp[(size_t)i * 4 + 3];
    float pn = (p - 0.5f) * 2.0f;
    v[0] = fminf(fmaxf(pn, 0.0f), 1.0f);
    v[1] = -fminf(fmaxf(pn, -1.0f), 0.0f);
    const float4* f4 = (const float4*)(feat + (size_t)i * FEAT);
#pragma unroll
    for (int j = 0; j < FEAT / 4; j++) {
        float4 t = f4[j];
        v[2 + 4 * j] = t.x; v[3 + 4 * j] = t.y; v[4 + 4 * j] = t.z; v[5 + 4 * j] = t.w;
    }
    float s = 0.0f;
#pragma unroll
    for (int j = 0; j < CIN; j++) s += v[j];
    float mu = s / (float)CIN;
    float vs = 0.0f;
#pragma unroll
    for (int j = 0; j < CIN; j++) { float d = v[j] - mu; vs += d * d; }
    float inv = 1.0f / sqrtf(vs / (float)CIN + 1e-5f);
    short* o = sp_bf + (size_t)i * 96;
#pragma unroll
    for (int j = 0; j < CIN; j++) o[j] = f2b((v[j] - mu) * inv * ln_g[j] + ln_b[j]);
#pragma unroll
    for (int j = CIN; j < 96; j++) o[j] = 0;
}

// ---------------- conv1 (MFMA): h1 = einsum(gather9(sp), W1) + b1 -> bf16 ----------------
__global__ __launch_bounds__(256) void k_conv1(const int* __restrict__ grid, const int* __restrict__ cxy,
                                               const short* __restrict__ sp_bf, const float* __restrict__ b1,
                                               const short* __restrict__ pk_w1, short* __restrict__ h1_bf) {
    __shared__ int sj[9][32];
    __shared__ __align__(16) char s_A[32 * 256];
    int row0 = blockIdx.x * 32;
    int b = row0 / NN;
    int tid = threadIdx.x;
    for (int e = tid; e < 9 * 32; e += 256) {
        int k = e / 32, p = e % 32;
        int me = cxy[row0 + p];
        int cx = me & 255, cy = (me >> 8) & 255;
        sj[k][p] = grid[b * GS * GS + (cy + k / 3) * GS + (cx + k % 3)];
    }
    int w = tid >> 6, l = tid & 63;
    f32x4 acc[2][2];
#pragma unroll
    for (int mt = 0; mt < 2; mt++)
#pragma unroll
        for (int nt = 0; nt < 2; nt++) acc[mt][nt] = (f32x4){0.f, 0.f, 0.f, 0.f};
    for (int tap = 0; tap < 9; ++tap) {
        __syncthreads();
        for (int e = tid; e < 384; e += 256) {
            int p = e / 12, ch = e % 12;
            int j = sj[tap][p];
            int4 val = {0, 0, 0, 0};
            if (j >= 0) val = *(const int4*)(sp_bf + ((size_t)(b * NN + j) * 96 + ch * 8));
            *(int4*)&s_A[p * 256 + ((ch * 16) ^ ((p & 7) << 4))] = val;
        }
        __syncthreads();
#pragma unroll
        for (int kt = 0; kt < 3; ++kt) {
            int r0a = (l & 15);
            bf16x8 a0 = *(const bf16x8*)&s_A[r0a * 256 + ((kt * 64 + (l >> 4) * 16) ^ ((r0a & 7) << 4))];
            int r1a = 16 + (l & 15);
            bf16x8 a1 = *(const bf16x8*)&s_A[r1a * 256 + ((kt * 64 + (l >> 4) * 16) ^ ((r1a & 7) << 4))];
#pragma unroll
            for (int nt = 0; nt < 2; ++nt) {
                bf16x8 bv = *(const bf16x8*)(pk_w1 + (size_t)(((tap * 3 + kt) * 8 + (w * 2 + nt)) * 64 + l) * 8);
                acc[0][nt] = MFMA_B16(a0, bv, acc[0][nt]);
                acc[1][nt] = MFMA_B16(a1, bv, acc[1][nt]);
            }
        }
    }
    int cl = l & 15;
#pragma unroll
    for (int nt = 0; nt < 2; ++nt) {
        int col = w * 32 + nt * 16 + cl;
        float bb = b1[col];
#pragma unroll
        for (int mt = 0; mt < 2; ++mt)
#pragma unroll
            for (int j = 0; j < 4; ++j) {
                int row = row0 + mt * 16 + (l >> 4) * 4 + j;
                h1_bf[(size_t)row * 128 + col] = f2b(acc[mt][nt][j] + bb);
            }
    }
}

// ---------------- conv2 (MFMA): h2 = einsum(gather9(h1), W2) -> q,k,v bf16 ----------------
__global__ __launch_bounds__(256) void k_conv2(const int* __restrict__ grid, const int* __restrict__ cxy,
                                               const short* __restrict__ h1_bf, const short* __restrict__ pk_w2,
                                               short* __restrict__ qg, short* __restrict__ kg, short* __restrict__ vg) {
    __shared__ int sj[9][32];
    __shared__ __align__(16) char s_A[32 * 256];
    int row0 = blockIdx.x * 32;
    int b = row0 / NN;
    int tid = threadIdx.x;
    for (int e = tid; e < 9 * 32; e += 256) {
        int k = e / 32, p = e % 32;
        int me = cxy[row0 + p];
        int cx = me & 255, cy = (me >> 8) & 255;
        sj[k][p] = grid[b * GS * GS + (cy + k / 3) * GS + (cx + k % 3)];
    }
    int w = tid >> 6, l = tid & 63;
    f32x4 acc[2][6];
#pragma unroll
    for (int mt = 0; mt < 2; mt++)
#pragma unroll
        for (int nt = 0; nt < 6; nt++) acc[mt][nt] = (f32x4){0.f, 0.f, 0.f, 0.f};
    for (int tap = 0; tap < 9; ++tap) {
        __syncthreads();
        for (int e = tid; e < 512; e += 256) {
            int p = e >> 4, ch = e & 15;
            int j = sj[tap][p];
            int4 val = {0, 0, 0, 0};
            if (j >= 0) val = *(const int4*)(h1_bf + ((size_t)(b * NN + j) * 128 + ch * 8));
            *(int4*)&s_A[p * 256 + ((ch * 16) ^ ((p & 7) << 4))] = val;
        }
        __syncthreads();
#pragma unroll
        for (int kt = 0; kt < 4; ++kt) {
            int r0a = (l & 15);
            bf16x8 a0 = *(const bf16x8*)&s_A[r0a * 256 + ((kt * 64 + (l >> 4) * 16) ^ ((r0a & 7) << 4))];
            int r1a = 16 + (l & 15);
            bf16x8 a1 = *(const bf16x8*)&s_A[r1a * 256 + ((kt * 64 + (l >> 4) * 16) ^ ((r1a & 7) << 4))];
#pragma unroll
            for (int nt = 0; nt < 6; ++nt) {
                bf16x8 bv = *(const bf16x8*)(pk_w2 + (size_t)(((tap * 4 + kt) * 24 + (w * 6 + nt)) * 64 + l) * 8);
                acc[0][nt] = MFMA_B16(a0, bv, acc[0][nt]);
                acc[1][nt] = MFMA_B16(a1, bv, acc[1][nt]);
            }
        }
    }
    int cl = l & 15;
#pragma unroll
    for (int nt = 0; nt < 6; ++nt) {
        int col = w * 96 + nt * 16 + cl;
        int s = col % 3, dd = col / 3;
        short* dst = (s == 0) ? qg : (s == 1) ? kg : vg;
#pragma unroll
        for (int mt = 0; mt < 2; ++mt)
#pragma unroll
            for (int j = 0; j < 4; ++j) {
                int row = row0 + mt * 16 + (l >> 4) * 4 + j;
                dst[(size_t)row * 128 + dd] = f2b(acc[mt][nt][j]);
            }
    }
}

// ---------------- fused attention (MFMA, barrier-free per-wave, async K/V gather) ----------------
__global__ __launch_bounds__(256) void k_attn(const float* __restrict__ xyzp, const int* __restrict__ idx,
                                              const short* __restrict__ qg, const short* __restrict__ kg,
                                              const short* __restrict__ vg,
                                              const float* __restrict__ pe_w1, const float* __restrict__ pe_b1,
                                              const float* __restrict__ pe_b2, const float* __restrict__ at_b1,
                                              const float* __restrict__ at_b2,
                                              const short* __restrict__ pk_pe2, const short* __restrict__ pk_a1,
                                              const short* __restrict__ pk_a2, float* __restrict__ res1) {
    __shared__ __align__(16) char s_A[128 * 256];   // hidden / t / relu, swizzle ((r&7)<<4)
    __shared__ __align__(16) char s_KV[128 * 256];  // K rows, then V rows; swizzle (((r>>2)&3)<<5)
    __shared__ int s_j[128];
    __shared__ float s_rel[128][3];
    int tid = threadIdx.x;
    int w = tid >> 6, l = tid & 63;
    int r0 = w * 32;
    int p0 = blockIdx.x * 8;
    int cl = l & 15;

    if (l < 32) {
        int rr = r0 + l;
        int P = p0 + (rr >> 4);
        int base = (P >> 12) << 12;
        int j = idx[(size_t)P * 16 + (rr & 15)];
        int g = base + j;
        s_j[rr] = g;
        s_rel[rr][0] = xyzp[(size_t)P * 4 + 0] - xyzp[(size_t)g * 4 + 0];
        s_rel[rr][1] = xyzp[(size_t)P * 4 + 1] - xyzp[(size_t)g * 4 + 1];
        s_rel[rr][2] = xyzp[(size_t)P * 4 + 3] - xyzp[(size_t)g * 4 + 3];
    }
    // Q prefetch (16 scalar u16 loads, issued early)
    unsigned short qpre[2][8];
#pragma unroll
    for (int mt = 0; mt < 2; ++mt) {
        int P = p0 + w * 2 + mt;
#pragma unroll
        for (int nt = 0; nt < 8; ++nt)
            qpre[mt][nt] = *(const unsigned short*)((const unsigned short*)qg + (size_t)P * 128 + nt * 16 + cl);
    }
    // K gather: async DMA, pre-swizzled global source so linear LDS write lands swizzled
#pragma unroll
    for (int it = 0; it < 8; ++it) {
        int row = r0 + it * 4 + (l >> 4);
        int g = s_j[row];
        int srcch = cl ^ ((it & 3) << 1);
        gload_lds16(kg + (size_t)g * 128 + srcch * 8, &s_KV[(r0 + it * 4) * 256]);
    }
    // PE1: hidden = relu(rel @ pe_w1 + pe_b1) -> s_A (hides K DMA + Q prefetch)
    {
        int c0 = 2 * l;
        float wa0 = pe_w1[c0], wa1 = pe_w1[c0 + 1];
        float wb0 = pe_w1[128 + c0], wb1 = pe_w1[129 + c0];
        float wc0 = pe_w1[256 + c0], wc1 = pe_w1[257 + c0];
        float ba0 = pe_b1[c0], ba1 = pe_b1[c0 + 1];
        for (int rr = r0; rr < r0 + 32; ++rr) {
            float rx = s_rel[rr][0], ry = s_rel[rr][1], rp = s_rel[rr][2];
            float h0 = fmaxf(rx * wa0 + ry * wb0 + rp * wc0 + ba0, 0.f);
            float h1v = fmaxf(rx * wa1 + ry * wb1 + rp * wc1 + ba1, 0.f);
            unsigned pk = (unsigned)(unsigned short)f2b(h0) | (((unsigned)(unsigned short)f2b(h1v)) << 16);
            *(unsigned*)&s_A[rr * 256 + ((c0 * 2) ^ ((rr & 7) << 4))] = pk;
        }
    }
    f32x4 pe_[2][8];
    f32x4 acc[2][8];
#pragma unroll
    for (int mt = 0; mt < 2; mt++)
#pragma unroll
        for (int nt = 0; nt < 8; nt++) pe_[mt][nt] = (f32x4){0.f, 0.f, 0.f, 0.f};
    // PE2 GEMM
#pragma unroll
    for (int kt = 0; kt < 4; ++kt) {
        int ra = r0 + (l & 15);
        bf16x8 a0 = *(const bf16x8*)&s_A[ra * 256 + ((kt * 64 + (l >> 4) * 16) ^ ((ra & 7) << 4))];
        int rb = ra + 16;
        bf16x8 a1 = *(const bf16x8*)&s_A[rb * 256 + ((kt * 64 + (l >> 4) * 16) ^ ((rb & 7) << 4))];
#pragma unroll
        for (int nt = 0; nt < 8; ++nt) {
            bf16x8 bv = *(const bf16x8*)(pk_pe2 + (size_t)((kt * 8 + nt) * 64 + l) * 8);
            pe_[0][nt] = MFMA_B16(a0, bv, pe_[0][nt]);
            pe_[1][nt] = MFMA_B16(a1, bv, pe_[1][nt]);
        }
    }
#pragma unroll
    for (int nt = 0; nt < 8; ++nt) {
        float b2v = pe_b2[nt * 16 + cl];
#pragma unroll
        for (int mt = 0; mt < 2; ++mt)
#pragma unroll
            for (int j = 0; j < 4; ++j) pe_[mt][nt][j] += b2v;
    }
    // wait for K DMA (and Q) to land, then build t = q - k + pe from LDS
    asm volatile("s_waitcnt vmcnt(0)" ::: "memory");
#pragma unroll
    for (int mt = 0; mt < 2; ++mt) {
#pragma unroll
        for (int nt = 0; nt < 8; ++nt) {
            int col = nt * 16 + cl;
            float qv = b2f((short)qpre[mt][nt]);
#pragma unroll
            for (int j = 0; j < 4; ++j) {
                int rr = r0 + mt * 16 + (l >> 4) * 4 + j;
                float kv = b2f(*(const short*)&s_KV[rr * 256 + ((col * 2) ^ (((rr >> 2) & 3) << 5))]);
                *(short*)&s_A[rr * 256 + ((col * 2) ^ ((rr & 7) << 4))] = f2b(qv - kv + pe_[mt][nt][j]);
            }
        }
    }
    // ensure all s_KV reads retired, then overwrite with V rows (hidden under A1+A2)
    asm volatile("s_waitcnt lgkmcnt(0)" ::: "memory");
#pragma unroll
    for (int it = 0; it < 8; ++it) {
        int row = r0 + it * 4 + (l >> 4);
        int g = s_j[row];
        int srcch = cl ^ ((it & 3) << 1);
        gload_lds16(vg + (size_t)g * 128 + srcch * 8, &s_KV[(r0 + it * 4) * 256]);
    }
    // A1 GEMM
#pragma unroll
    for (int mt = 0; mt < 2; mt++)
#pragma unroll
        for (int nt = 0; nt < 8; nt++) acc[mt][nt] = (f32x4){0.f, 0.f, 0.f, 0.f};
#pragma unroll
    for (int kt = 0; kt < 4; ++kt) {
        int ra = r0 + (l & 15);
        bf16x8 a0 = *(const bf16x8*)&s_A[ra * 256 + ((kt * 64 + (l >> 4) * 16) ^ ((ra & 7) << 4))];
        int rb = ra + 16;
        bf16x8 a1 = *(const bf16x8*)&s_A[rb * 256 + ((kt * 64 + (l >> 4) * 16) ^ ((rb & 7) << 4))];
#pragma unroll
        for (int nt = 0; nt < 8; ++nt) {
            bf16x8 bv = *(const bf16x8*)(pk_a1 + (size_t)((kt * 8 + nt) * 64 + l) * 8);
            acc[0][nt] = MFMA_B16(a0, bv, acc[0][nt]);
            acc[1][nt] = MFMA_B16(a1, bv, acc[1][nt]);
        }
    }
    // relu(+at_b1) -> s_A
#pragma unroll
    for (int nt = 0; nt < 8; ++nt) {
        float bv = at_b1[nt * 16 + cl];
        int col = nt * 16 + cl;
#pragma unroll
        for (int mt = 0; mt < 2; ++mt)
#pragma unroll
            for (int j = 0; j < 4; ++j) {
                int rr = r0 + mt * 16 + (l >> 4) * 4 + j;
                *(short*)&s_A[rr * 256 + ((col * 2) ^ ((rr & 7) << 4))] = f2b(fmaxf(acc[mt][nt][j] + bv, 0.f));
            }
    }
    // A2 GEMM
#pragma unroll
    for (int mt = 0; mt < 2; mt++)
#pragma unroll
        for (int nt = 0; nt < 8; nt++) acc[mt][nt] = (f32x4){0.f, 0.f, 0.f, 0.f};
#pragma unroll
    for (int kt = 0; kt < 4; ++kt) {
        int ra = r0 + (l & 15);
        bf16x8 a0 = *(const bf16x8*)&s_A[ra * 256 + ((kt * 64 + (l >> 4) * 16) ^ ((ra & 7) << 4))];
        int rb = ra + 16;
        bf16x8 a1 = *(const bf16x8*)&s_A[rb * 256 + ((kt * 64 + (l >> 4) * 16) ^ ((rb & 7) << 4))];
#pragma unroll
        for (int nt = 0; nt < 8; ++nt) {
            bf16x8 bv = *(const bf16x8*)(pk_a2 + (size_t)((kt * 8 + nt) * 64 + l) * 8);
            acc[0][nt] = MFMA_B16(a0, bv, acc[0][nt]);
            acc[1][nt] = MFMA_B16(a1, bv, acc[1][nt]);
        }
    }
    // wait for V DMA, softmax over K + weighted (v+pe) sum
    asm volatile("s_waitcnt vmcnt(0)" ::: "memory");
    const float scale = 0.08838834764831845f;
#pragma unroll
    for (int mt = 0; mt < 2; ++mt) {
        int P = p0 + w * 2 + mt;
#pragma unroll
        for (int nt = 0; nt < 8; ++nt) {
            int col = nt * 16 + cl;
            float bv = at_b2[col];
            float vv[4];
#pragma unroll
            for (int j = 0; j < 4; ++j) vv[j] = (acc[mt][nt][j] + bv) * scale;
            float m = fmaxf(fmaxf(vv[0], vv[1]), fmaxf(vv[2], vv[3]));
            m = fmaxf(m, __shfl_xor(m, 16));
            m = fmaxf(m, __shfl_xor(m, 32));
            float ee[4], es = 0.f;
#pragma unroll
            for (int j = 0; j < 4; ++j) { ee[j] = __expf(vv[j] - m); es += ee[j]; }
            es += __shfl_xor(es, 16);
            es += __shfl_xor(es, 32);
            float o = 0.f;
#pragma unroll
            for (int j = 0; j < 4; ++j) {
                int rr = r0 + mt * 16 + (l >> 4) * 4 + j;
                float vvv = b2f(*(const short*)&s_KV[rr * 256 + ((col * 2) ^ (((rr >> 2) & 3) << 5))]);
                o += ee[j] * (vvv + pe_[mt][nt][j]);
            }
            o += __shfl_xor(o, 16);
            o += __shfl_xor(o, 32);
            if (l < 16) res1[(size_t)P * 128 + col] = o / es;
        }
    }
}

// ---------------- final head (f32 VALU) ----------------
__global__ __launch_bounds__(256) void k_head(const float* __restrict__ res1, const float* __restrict__ feat,
                                              const float* __restrict__ ag_w, const float* __restrict__ ag_b,
                                              const float* __restrict__ mlp_w1, const float* __restrict__ mlp_b1,
                                              const float* __restrict__ mlp_w2, const float* __restrict__ mlp_b2,
                                              float* __restrict__ out) {
    __shared__ __align__(16) float rs[64][128];
    __shared__ __align__(16) float r1s[64][64];
    int tid = threadIdx.x;
    int i0 = blockIdx.x * 64;
    for (int e = tid; e < 64 * 128; e += 256) rs[e >> 7][e & 127] = res1[(size_t)i0 * 128 + e];
    __syncthreads();
    {
        int d = tid & 63, rg = tid >> 6;
        float acc[16];
#pragma unroll
        for (int i = 0; i < 16; i++) acc[i] = 0.0f;
        for (int c4 = 0; c4 < 32; ++c4) {
            int c = c4 * 4;
            float w0 = ag_w[c * 64 + d], w1 = ag_w[(c + 1) * 64 + d];
            float w2 = ag_w[(c + 2) * 64 + d], w3 = ag_w[(c + 3) * 64 + d];
#pragma unroll
            for (int i = 0; i < 16; i++) {
                float4 f = *(const float4*)&rs[rg * 16 + i][c];
                acc[i] += f.x * w0 + f.y * w1 + f.z * w2 + f.w * w3;
            }
        }
        float bb = ag_b[d];
#pragma unroll
        for (int i = 0; i < 16; i++) {
            int pp = rg * 16 + i;
            r1s[pp][d] = acc[i] + bb + feat[(size_t)(i0 + pp) * 64 + d];
        }
    }
    __syncthreads();
    {
        int d = tid & 127, rg = tid >> 7;
        float acc[32];
#pragma unroll
        for (int i = 0; i < 32; i++) acc[i] = 0.0f;
        for (int c4 = 0; c4 < 16; ++c4) {
            int c = c4 * 4;
            float w0 = mlp_w1[c * 128 + d], w1 = mlp_w1[(c + 1) * 128 + d];
            float w2 = mlp_w1[(c + 2) * 128 + d], w3 = mlp_w1[(c + 3) * 128 + d];
#pragma unroll
            for (int i = 0; i < 32; i++) {
                float4 f = *(const float4*)&r1s[rg * 32 + i][c];
                acc[i] += f.x * w0 + f.y * w1 + f.z * w2 + f.w * w3;
            }
        }
        float bb = mlp_b1[d];
#pragma unroll
        for (int i = 0; i < 32; i++) {
            float x = acc[i] + bb;
            rs[rg * 32 + i][d] = 0.5f * x * (1.0f + erff(x * 0.70710678118654752f));
        }
    }
    __syncthreads();
    {
        int d = tid & 63, rg = tid >> 6;
        float acc[16];
#pragma unroll
        for (int i = 0; i < 16; i++) acc[i] = 0.0f;
        for (int c4 = 0; c4 < 32; ++c4) {
            int c = c4 * 4;
            float w0 = mlp_w2[c * 64 + d], w1 = mlp_w2[(c + 1) * 64 + d];
            float w2 = mlp_w2[(c + 2) * 64 + d], w3 = mlp_w2[(c + 3) * 64 + d];
#pragma unroll
            for (int i = 0; i < 16; i++) {
                float4 f = *(const float4*)&rs[rg * 16 + i][c];
                acc[i] += f.x * w0 + f.y * w1 + f.z * w2 + f.w * w3;
            }
        }
        float bb = mlp_b2[d];
#pragma unroll
        for (int i = 0; i < 16; i++) {
            int pp = rg * 16 + i;
            out[(size_t)(i0 + pp) * 64 + d] = acc[i] + bb + feat[(size_t)(i0 + pp) * 64 + d];
        }
    }
}

extern "C" void kernel_launch(void* const* d_in, const int* in_sizes, int n_in,
                              void* d_out, int out_size, void* d_ws, size_t ws_size,
                              hipStream_t stream) {
    const float* xyzp = (const float*)d_in[0];
    const float* features = (const float*)d_in[1];
    const float* ln_g = (const float*)d_in[2];
    const float* ln_b = (const float*)d_in[3];
    const float* W1 = (const float*)d_in[4];
    const float* b1 = (const float*)d_in[5];
    const float* W2 = (const float*)d_in[6];
    const float* pe_w1 = (const float*)d_in[7];
    const float* pe_b1 = (const float*)d_in[8];
    const float* pe_w2 = (const float*)d_in[9];
    const float* pe_b2 = (const float*)d_in[10];
    const float* at_w1 = (const float*)d_in[11];
    const float* at_b1 = (const float*)d_in[12];
    const float* at_w2 = (const float*)d_in[13];
    const float* at_b2 = (const float*)d_in[14];
    const float* ag_w = (const float*)d_in[15];
    const float* ag_b = (const float*)d_in[16];
    const float* mlp_w1 = (const float*)d_in[17];
    const float* mlp_b1 = (const float*)d_in[18];
    const float* mlp_w2 = (const float*)d_in[19];
    const float* mlp_b2 = (const float*)d_in[20];
    float* out = (float*)d_out;

    char* w = (char*)d_ws;
    auto alloc = [&](size_t bytes) { char* pp = w; w += (bytes + 255) & ~(size_t)255; return pp; };
    int* grid = (int*)alloc((size_t)BB * GS * GS * 4);
    int* cxy = (int*)alloc((size_t)BB * NN * 4);
    unsigned* part = (unsigned*)alloc((size_t)BB * NN * NC * KNN * 4);
    int* idxb = (int*)alloc((size_t)BB * NN * KNN * 4);
    short* sp_bf = (short*)alloc((size_t)BB * NN * 96 * 2);
    short* h1_bf = (short*)alloc((size_t)BB * NN * HID * 2);
    short* qg = (short*)alloc((size_t)BB * NN * HID * 2);
    short* kg = (short*)alloc((size_t)BB * NN * HID * 2);
    short* vg = (short*)alloc((size_t)BB * NN * HID * 2);
    float* res1 = (float*)alloc((size_t)BB * NN * HID * 4);
    short* pk_pe2 = (short*)alloc((size_t)PK128_SZ * 2);
    short* pk_a1 = (short*)alloc((size_t)PK128_SZ * 2);
    short* pk_a2 = (short*)alloc((size_t)PK128_SZ * 2);
    short* pk_w1 = (short*)alloc((size_t)PKW1_SZ * 2);
    short* pk_w2 = (short*)alloc((size_t)PKW2_SZ * 2);

    k_grid_init<<<(BB * GS * GS + 255) / 256, 256, 0, stream>>>(grid);
    k_scatter<<<(BB * NN + 255) / 256, 256, 0, stream>>>(xyzp, grid, cxy);
    k_pack<<<(3 * PK128_SZ + PKW1_SZ + PKW2_SZ + 255) / 256, 256, 0, stream>>>(
        pe_w2, at_w1, at_w2, W1, W2, pk_pe2, pk_a1, pk_a2, pk_w1, pk_w2);
    k_knn_part<<<BB * (NN / 256) * NC, 256, 0, stream>>>(cxy, part);
    k_knn_merge<<<BB * NN / 64, 64, 0, stream>>>(part, idxb);
    k_sp<<<(BB * NN + 255) / 256, 256, 0, stream>>>(xyzp, features, ln_g, ln_b, sp_bf);
    k_conv1<<<BB * NN / 32, 256, 0, stream>>>(grid, cxy, sp_bf, b1, pk_w1, h1_bf);
    k_conv2<<<BB * NN / 32, 256, 0, stream>>>(grid, cxy, h1_bf, pk_w2, qg, kg, vg);
    k_attn<<<BB * NN / 8, 256, 0, stream>>>(xyzp, idxb, qg, kg, vg, pe_w1, pe_b1, pe_b2, at_b1, at_b2,
                                            pk_pe2, pk_a1, pk_a2, res1);
    k_head<<<BB * NN / 64, 256, 0, stream>>>(res1, features, ag_w, ag_b, mlp_w1, mlp_b1, mlp_w2, mlp_b2, out);
}

// Round 4
// 436.028 us; speedup vs baseline: 2.8318x; 1.0653x over previous
//
#include <hip/hip_runtime.h>
#include <math.h>

#define BB 4
#define NN 4096
#define FEAT 64
#define HID 128
#define KNN 16
#define GS 258
#define CIN 66
#define NC 8
#define CHUNK (NN / NC)

typedef __attribute__((ext_vector_type(8))) short bf16x8;
typedef __attribute__((ext_vector_type(4))) float f32x4;
#define MFMA_B16(a, b, c) __builtin_amdgcn_mfma_f32_16x16x32_bf16(a, b, c, 0, 0, 0)

__device__ __forceinline__ short f2b(float f) {
    unsigned u = __builtin_bit_cast(unsigned, f);
    u = (u + 0x7FFFu + ((u >> 16) & 1u)) >> 16;
    return (short)u;
}
__device__ __forceinline__ float b2f(short s) {
    return __builtin_bit_cast(float, ((unsigned)(unsigned short)s) << 16);
}
__device__ __forceinline__ void gload_lds16(const void* g, void* lds) {
    __builtin_amdgcn_global_load_lds((const __attribute__((address_space(1))) unsigned int*)g,
                                     (__attribute__((address_space(3))) unsigned int*)lds, 16, 0, 0);
}

// ---------------- grid build (+ zero page) ----------------
__global__ void k_grid_init(int* grid, short* zero256) {
    int i = blockIdx.x * 256 + threadIdx.x;
    if (i < BB * GS * GS) grid[i] = -1;
    int z = i - BB * GS * GS;
    if (z >= 0 && z < 128) zero256[z] = 0;
}

__global__ void k_scatter(const float* __restrict__ xyzp, int* __restrict__ grid, int* __restrict__ cxy) {
    int i = blockIdx.x * 256 + threadIdx.x;
    if (i >= BB * NN) return;
    int b = i / NN, n = i % NN;
    float x = xyzp[(size_t)i * 4 + 0], y = xyzp[(size_t)i * 4 + 1];
    int cx = __float2int_rn(x * 256.0f);
    int cy = __float2int_rn(y * 256.0f);
    cxy[i] = cx | (cy << 8);
    grid[b * GS * GS + (cy + 1) * GS + (cx + 1)] = n;
}

// ---------------- exact KNN (integer d2, tie-break lower index) ----------------
__global__ __launch_bounds__(256) void k_knn_part(const int* __restrict__ cxy, unsigned* __restrict__ part) {
    int bid = blockIdx.x;
    int ch = bid % NC; bid /= NC;
    int qb = bid % (NN / 256);
    int b = bid / (NN / 256);
    int n = qb * 256 + threadIdx.x;
    __shared__ int sc[CHUNK];
    for (int t = threadIdx.x; t < CHUNK; t += 256) sc[t] = cxy[b * NN + ch * CHUNK + t];
    __syncthreads();
    int me = cxy[b * NN + n];
    int mx = me & 255, my = (me >> 8) & 255;
    unsigned a[KNN];
#pragma unroll
    for (int j = 0; j < KNN; j++) a[j] = 0xFFFFFFFFu;
    for (int t = 0; t < CHUNK; ++t) {
        int c = sc[t];
        int dx = mx - (c & 255), dy = my - ((c >> 8) & 255);
        unsigned d2 = (unsigned)(dx * dx + dy * dy);
        unsigned key = (d2 << 12) | (unsigned)(ch * CHUNK + t);
        if (key < a[KNN - 1]) {
#pragma unroll
            for (int j = KNN - 1; j >= 1; --j) {
                unsigned prev = a[j - 1];
                a[j] = (prev > key) ? prev : ((a[j] > key) ? key : a[j]);
            }
            a[0] = a[0] < key ? a[0] : key;
        }
    }
    unsigned* dst = part + ((size_t)(b * NN + n) * NC + ch) * KNN;
#pragma unroll
    for (int j = 0; j < KNN; j++) dst[j] = a[j];
}

__global__ __launch_bounds__(64) void k_knn_merge(const unsigned* __restrict__ part, int* __restrict__ idxo) {
    int q = blockIdx.x * 64 + threadIdx.x;
    if (q >= BB * NN) return;
    unsigned a[KNN];
#pragma unroll
    for (int j = 0; j < KNN; j++) a[j] = 0xFFFFFFFFu;
    for (int ch = 0; ch < NC; ++ch) {
#pragma unroll
        for (int j = 0; j < KNN; j++) {
            unsigned key = part[((size_t)q * NC + ch) * KNN + j];
            if (key < a[KNN - 1]) {
#pragma unroll
                for (int t = KNN - 1; t >= 1; --t) {
                    unsigned prev = a[t - 1];
                    a[t] = (prev > key) ? prev : ((a[t] > key) ? key : a[t]);
                }
                a[0] = a[0] < key ? a[0] : key;
            }
        }
    }
#pragma unroll
    for (int j = 0; j < KNN; j++) idxo[(size_t)q * KNN + j] = (int)(a[j] & 4095u);
}

// ---------------- rel/g table: relg[i] = {x-xg, y-yg, p-pg, g} ----------------
__global__ __launch_bounds__(256) void k_prep(const float* __restrict__ xyzp, const int* __restrict__ idxb,
                                              float4* __restrict__ relg) {
    int i = blockIdx.x * 256 + threadIdx.x;
    if (i >= BB * NN * KNN) return;
    int P = i >> 4;
    int base = P & ~(NN - 1);
    int g = base + idxb[i];
    float4 a = *(const float4*)(xyzp + (size_t)P * 4);
    float4 bq = *(const float4*)(xyzp + (size_t)g * 4);
    float4 o;
    o.x = a.x - bq.x; o.y = a.y - bq.y; o.z = a.w - bq.w;
    o.w = __int_as_float(g);
    relg[i] = o;
}

// ---------------- weight pre-pack into bf16 MFMA B-fragments ----------------
#define PK128_SZ (4 * 8 * 512)
#define PKW1_SZ (9 * 3 * 8 * 512)
#define PKW2_SZ (9 * 4 * 24 * 512)

__global__ __launch_bounds__(256) void k_pack(const float* __restrict__ pe_w2, const float* __restrict__ at_w1,
                                              const float* __restrict__ at_w2, const float* __restrict__ W1,
                                              const float* __restrict__ W2,
                                              short* __restrict__ pk_pe2, short* __restrict__ pk_a1,
                                              short* __restrict__ pk_a2, short* __restrict__ pk_w1,
                                              short* __restrict__ pk_w2) {
    int i = blockIdx.x * 256 + threadIdx.x;
    if (i < 3 * PK128_SZ) {
        int seg = i / PK128_SZ, r = i % PK128_SZ;
        int f = r / 512, q = r % 512;
        int lane = q / 8, j = q % 8;
        int kt = f / 8, nt = f % 8;
        int k = kt * 32 + (lane >> 4) * 8 + j, n = nt * 16 + (lane & 15);
        const float* W = (seg == 0) ? pe_w2 : (seg == 1) ? at_w1 : at_w2;
        short* dst = (seg == 0) ? pk_pe2 : (seg == 1) ? pk_a1 : pk_a2;
        dst[r] = f2b(W[k * 128 + n]);
        return;
    }
    i -= 3 * PK128_SZ;
    if (i < PKW1_SZ) {
        int f = i / 512, q = i % 512;
        int lane = q / 8, j = q % 8;
        int tap = f / 24, rem = f % 24;
        int kt = rem / 8, nt = rem % 8;
        int k = kt * 32 + (lane >> 4) * 8 + j, n = nt * 16 + (lane & 15);
        pk_w1[i] = (k < CIN) ? f2b(W1[(tap * CIN + k) * 128 + n]) : (short)0;
        return;
    }
    i -= PKW1_SZ;
    if (i < PKW2_SZ) {
        int f = i / 512, q = i % 512;
        int lane = q / 8, j = q % 8;
        int tap = f / 96, rem = f % 96;
        int kt = rem / 24, nt = rem % 24;
        int k = kt * 32 + (lane >> 4) * 8 + j, n = nt * 16 + (lane & 15);
        pk_w2[i] = f2b(W2[((size_t)(tap * 128 + k)) * 384 + n]);
    }
}

// ---------------- sp = LayerNorm(...) -> bf16, padded to 128 cols ----------------
__global__ __launch_bounds__(256) void k_sp(const float* __restrict__ xyzp, const float* __restrict__ feat,
                                            const float* __restrict__ ln_g, const float* __restrict__ ln_b,
                                            short* __restrict__ sp_bf) {
    int i = blockIdx.x * 256 + threadIdx.x;
    if (i >= BB * NN) return;
    float v[CIN];
    float p = xyzp[(size_t)i * 4 + 3];
    float pn = (p - 0.5f) * 2.0f;
    v[0] = fminf(fmaxf(pn, 0.0f), 1.0f);
    v[1] = -fminf(fmaxf(pn, -1.0f), 0.0f);
    const float4* f4 = (const float4*)(feat + (size_t)i * FEAT);
#pragma unroll
    for (int j = 0; j < FEAT / 4; j++) {
        float4 t = f4[j];
        v[2 + 4 * j] = t.x; v[3 + 4 * j] = t.y; v[4 + 4 * j] = t.z; v[5 + 4 * j] = t.w;
    }
    float s = 0.0f;
#pragma unroll
    for (int j = 0; j < CIN; j++) s += v[j];
    float mu = s / (float)CIN;
    float vs = 0.0f;
#pragma unroll
    for (int j = 0; j < CIN; j++) { float d = v[j] - mu; vs += d * d; }
    float inv = 1.0f / sqrtf(vs / (float)CIN + 1e-5f);
    short* o = sp_bf + (size_t)i * 128;
#pragma unroll
    for (int j = 0; j < CIN; j++) o[j] = f2b((v[j] - mu) * inv * ln_g[j] + ln_b[j]);
#pragma unroll
    for (int j = CIN; j < 128; j++) o[j] = 0;
}

// ---------------- conv1 (MFMA, 64-row blocks, DMA double-buffered) ----------------
__global__ __launch_bounds__(256) void k_conv1(const int* __restrict__ grid, const int* __restrict__ cxy,
                                               const short* __restrict__ sp_bf, const float* __restrict__ b1,
                                               const short* __restrict__ pk_w1, const short* __restrict__ zero256,
                                               short* __restrict__ h1_bf) {
    __shared__ int sj[9][64];
    __shared__ __align__(16) char sb[2][64 * 256];
    int row0 = blockIdx.x * 64;
    int b = row0 / NN;
    int tid = threadIdx.x;
    int w = tid >> 6, l = tid & 63, cl = l & 15;
    for (int e = tid; e < 9 * 64; e += 256) {
        int k = e / 64, p = e % 64;
        int me = cxy[row0 + p];
        sj[k][p] = grid[b * GS * GS + (((me >> 8) & 255) + k / 3) * GS + ((me & 255) + k % 3)];
    }
    __syncthreads();
    f32x4 acc[4][2];
#pragma unroll
    for (int m = 0; m < 4; m++)
#pragma unroll
        for (int nt = 0; nt < 2; nt++) acc[m][nt] = (f32x4){0.f, 0.f, 0.f, 0.f};

#define STAGE1(bufp, tap)                                                                      \
    {                                                                                          \
        _Pragma("unroll") for (int i = 0; i < 4; ++i) {                                        \
            int row = w * 16 + i * 4 + (l >> 4);                                               \
            int j = sj[tap][row];                                                              \
            int srcch = cl ^ (row & 7);                                                        \
            const short* src = (j >= 0) ? (sp_bf + ((size_t)(b * NN + j) * 128 + srcch * 8))   \
                                        : (zero256 + srcch * 8);                               \
            gload_lds16(src, (bufp) + (w * 16 + i * 4) * 256);                                 \
        }                                                                                      \
    }
    STAGE1(&sb[0][0], 0);
    asm volatile("s_waitcnt vmcnt(0)" ::: "memory");
    __syncthreads();
    int cur = 0;
    for (int tap = 0; tap < 9; ++tap) {
        if (tap < 8) STAGE1(&sb[cur ^ 1][0], tap + 1);
        const char* base = &sb[cur][0];
#pragma unroll
        for (int kt = 0; kt < 3; ++kt) {
            bf16x8 a[4];
#pragma unroll
            for (int m = 0; m < 4; ++m) {
                int row = m * 16 + (l & 15);
                a[m] = *(const bf16x8*)&base[row * 256 + ((kt * 64 + (l >> 4) * 16) ^ ((row & 7) << 4))];
            }
#pragma unroll
            for (int nt = 0; nt < 2; ++nt) {
                bf16x8 bv = *(const bf16x8*)(pk_w1 + (size_t)(((tap * 3 + kt) * 8 + w * 2 + nt) * 64 + l) * 8);
#pragma unroll
                for (int m = 0; m < 4; ++m) acc[m][nt] = MFMA_B16(a[m], bv, acc[m][nt]);
            }
        }
        asm volatile("s_waitcnt vmcnt(0)" ::: "memory");
        __syncthreads();
        cur ^= 1;
    }
#pragma unroll
    for (int nt = 0; nt < 2; ++nt) {
        int col = (w * 2 + nt) * 16 + cl;
        float bb = b1[col];
#pragma unroll
        for (int m = 0; m < 4; ++m)
#pragma unroll
            for (int j = 0; j < 4; ++j) {
                int row = row0 + m * 16 + (l >> 4) * 4 + j;
                h1_bf[(size_t)row * 128 + col] = f2b(acc[m][nt][j] + bb);
            }
    }
}

// ---------------- conv2 (MFMA, 64-row blocks, DMA double-buffered) ----------------
__global__ __launch_bounds__(256) void k_conv2(const int* __restrict__ grid, const int* __restrict__ cxy,
                                               const short* __restrict__ h1_bf, const short* __restrict__ pk_w2,
                                               const short* __restrict__ zero256,
                                               short* __restrict__ qg, short* __restrict__ kg, short* __restrict__ vg) {
    __shared__ int sj[9][64];
    __shared__ __align__(16) char sb[2][64 * 256];
    int bid = blockIdx.x;
    int nb = bid % 3, mb = bid / 3;
    int row0 = mb * 64;
    int b = row0 / NN;
    int tid = threadIdx.x;
    int w = tid >> 6, l = tid & 63, cl = l & 15;
    for (int e = tid; e < 9 * 64; e += 256) {
        int k = e / 64, p = e % 64;
        int me = cxy[row0 + p];
        sj[k][p] = grid[b * GS * GS + (((me >> 8) & 255) + k / 3) * GS + ((me & 255) + k % 3)];
    }
    __syncthreads();
    f32x4 acc[4][2];
#pragma unroll
    for (int m = 0; m < 4; m++)
#pragma unroll
        for (int nt = 0; nt < 2; nt++) acc[m][nt] = (f32x4){0.f, 0.f, 0.f, 0.f};

#define STAGE2(bufp, tap)                                                                      \
    {                                                                                          \
        _Pragma("unroll") for (int i = 0; i < 4; ++i) {                                        \
            int row = w * 16 + i * 4 + (l >> 4);                                               \
            int j = sj[tap][row];                                                              \
            int srcch = cl ^ (row & 7);                                                        \
            const short* src = (j >= 0) ? (h1_bf + ((size_t)(b * NN + j) * 128 + srcch * 8))   \
                                        : (zero256 + srcch * 8);                               \
            gload_lds16(src, (bufp) + (w * 16 + i * 4) * 256);                                 \
        }                                                                                      \
    }
    STAGE2(&sb[0][0], 0);
    asm volatile("s_waitcnt vmcnt(0)" ::: "memory");
    __syncthreads();
    int cur = 0;
    for (int tap = 0; tap < 9; ++tap) {
        if (tap < 8) STAGE2(&sb[cur ^ 1][0], tap + 1);
        const char* base = &sb[cur][0];
#pragma unroll
        for (int kt = 0; kt < 4; ++kt) {
            bf16x8 a[4];
#pragma unroll
            for (int m = 0; m < 4; ++m) {
                int row = m * 16 + (l & 15);
                a[m] = *(const bf16x8*)&base[row * 256 + ((kt * 64 + (l >> 4) * 16) ^ ((row & 7) << 4))];
            }
#pragma unroll
            for (int nt = 0; nt < 2; ++nt) {
                bf16x8 bv = *(const bf16x8*)(pk_w2 + (size_t)(((tap * 4 + kt) * 24 + nb * 8 + w * 2 + nt) * 64 + l) * 8);
#pragma unroll
                for (int m = 0; m < 4; ++m) acc[m][nt] = MFMA_B16(a[m], bv, acc[m][nt]);
            }
        }
        asm volatile("s_waitcnt vmcnt(0)" ::: "memory");
        __syncthreads();
        cur ^= 1;
    }
#pragma unroll
    for (int nt = 0; nt < 2; ++nt) {
        int col = nb * 128 + (w * 2 + nt) * 16 + cl;
        int s = col % 3, dd = col / 3;
        short* dst = (s == 0) ? qg : (s == 1) ? kg : vg;
#pragma unroll
        for (int m = 0; m < 4; ++m)
#pragma unroll
            for (int j = 0; j < 4; ++j) {
                int row = row0 + m * 16 + (l >> 4) * 4 + j;
                dst[(size_t)row * 128 + dd] = f2b(acc[m][nt][j]);
            }
    }
}

// ---------------- fused attention (MFMA, per-wave private, reg-built t) ----------------
__global__ __launch_bounds__(256) void k_attn(const float4* __restrict__ relg,
                                              const short* __restrict__ qg, const short* __restrict__ kg,
                                              const short* __restrict__ vg,
                                              const float* __restrict__ pe_w1, const float* __restrict__ pe_b1,
                                              const float* __restrict__ pe_b2, const float* __restrict__ at_b1,
                                              const float* __restrict__ at_b2,
                                              const short* __restrict__ pk_pe2, const short* __restrict__ pk_a1,
                                              const short* __restrict__ pk_a2, float* __restrict__ res1) {
    __shared__ __align__(16) char s_work[4 * 8192];  // per-wave 32 rows x 256B: hidden -> pe -> relu
    __shared__ __align__(16) char s_kv[4 * 8192];    // per-wave 32 rows x 256B: K -> V
    __shared__ float4 s_rel[128];
    int tid = threadIdx.x;
    int w = tid >> 6, l = tid & 63;
    int r0 = w * 32;
    int p0 = blockIdx.x * 8;
    int cl = l & 15;
    char* WK = s_work + w * 8192;
    char* KV = s_kv + w * 8192;

    int g_reg = 0;
    if (l < 32) {
        float4 f4 = relg[(size_t)p0 * 16 + r0 + l];
        s_rel[r0 + l] = f4;
        g_reg = __float_as_int(f4.w);
    }
    // Q prefetch as A-fragments (b128, issued early)
    bf16x8 qf[2][4];
#pragma unroll
    for (int mt = 0; mt < 2; ++mt) {
        int P = p0 + w * 2 + mt;
#pragma unroll
        for (int kt = 0; kt < 4; ++kt)
            qf[mt][kt] = *(const bf16x8*)(qg + (size_t)P * 128 + kt * 32 + (l >> 4) * 8);
    }
    // K gather DMA: linear dest + slot-preswizzled source (srcch = cl ^ (row&7))
#pragma unroll
    for (int it = 0; it < 8; ++it) {
        int g = __shfl(g_reg, it * 4 + (l >> 4));
        int srcch = cl ^ ((it * 4 + (l >> 4)) & 7);
        gload_lds16(kg + (size_t)g * 128 + srcch * 8, KV + it * 1024);
    }
    // PE1: hidden = relu(rel @ pe_w1 + pe_b1) -> WK (hides K DMA)
    {
        int c0 = 2 * l;
        float wa0 = pe_w1[c0], wa1 = pe_w1[c0 + 1];
        float wb0 = pe_w1[128 + c0], wb1 = pe_w1[129 + c0];
        float wc0 = pe_w1[256 + c0], wc1 = pe_w1[257 + c0];
        float ba0 = pe_b1[c0], ba1 = pe_b1[c0 + 1];
        for (int lr = 0; lr < 32; ++lr) {
            float4 rel = s_rel[r0 + lr];
            float h0 = fmaxf(rel.x * wa0 + rel.y * wb0 + rel.z * wc0 + ba0, 0.f);
            float h1v = fmaxf(rel.x * wa1 + rel.y * wb1 + rel.z * wc1 + ba1, 0.f);
            unsigned pk = (unsigned)(unsigned short)f2b(h0) | (((unsigned)(unsigned short)f2b(h1v)) << 16);
            *(unsigned*)&WK[lr * 256 + ((4 * l) ^ ((lr & 7) << 4))] = pk;
        }
    }
    // PE2 GEMM -> pe_ (C-layout regs)
    f32x4 pe_[2][8];
#pragma unroll
    for (int mt = 0; mt < 2; mt++)
#pragma unroll
        for (int nt = 0; nt < 8; nt++) pe_[mt][nt] = (f32x4){0.f, 0.f, 0.f, 0.f};
#pragma unroll
    for (int kt = 0; kt < 4; ++kt) {
        int ra = (l & 15), rb = 16 + (l & 15);
        int off = kt * 64 + (l >> 4) * 16;
        bf16x8 a0 = *(const bf16x8*)&WK[ra * 256 + (off ^ ((ra & 7) << 4))];
        bf16x8 a1 = *(const bf16x8*)&WK[rb * 256 + (off ^ ((rb & 7) << 4))];
#pragma unroll
        for (int nt = 0; nt < 8; ++nt) {
            bf16x8 bv = *(const bf16x8*)(pk_pe2 + (size_t)((kt * 8 + nt) * 64 + l) * 8);
            pe_[0][nt] = MFMA_B16(a0, bv, pe_[0][nt]);
            pe_[1][nt] = MFMA_B16(a1, bv, pe_[1][nt]);
        }
    }
#pragma unroll
    for (int nt = 0; nt < 8; ++nt) {
        float b2v = pe_b2[nt * 16 + cl];
#pragma unroll
        for (int mt = 0; mt < 2; ++mt)
#pragma unroll
            for (int j = 0; j < 4; ++j) pe_[mt][nt][j] += b2v;
    }
    // pe -> WK (bf16, overwrites hidden; A-layout swizzle)
#pragma unroll
    for (int nt = 0; nt < 8; ++nt) {
        int col = nt * 16 + cl;
#pragma unroll
        for (int mt = 0; mt < 2; ++mt)
#pragma unroll
            for (int j = 0; j < 4; ++j) {
                int lr = mt * 16 + (l >> 4) * 4 + j;
                *(short*)&WK[lr * 256 + ((col * 2) ^ ((lr & 7) << 4))] = f2b(pe_[mt][nt][j]);
            }
    }
    // wait K DMA; build t = q - k + pe in registers (A-fragments) feeding A1 directly
    asm volatile("s_waitcnt vmcnt(0)" ::: "memory");
    f32x4 acc[2][8];
#pragma unroll
    for (int mt = 0; mt < 2; mt++)
#pragma unroll
        for (int nt = 0; nt < 8; nt++) acc[mt][nt] = (f32x4){0.f, 0.f, 0.f, 0.f};
#pragma unroll
    for (int kt = 0; kt < 4; ++kt) {
        int ra = (l & 15), rb = 16 + (l & 15);
        int off = kt * 64 + (l >> 4) * 16;
        bf16x8 pA = *(const bf16x8*)&WK[ra * 256 + (off ^ ((ra & 7) << 4))];
        bf16x8 pB = *(const bf16x8*)&WK[rb * 256 + (off ^ ((rb & 7) << 4))];
        bf16x8 kA = *(const bf16x8*)&KV[ra * 256 + (off ^ ((ra & 7) << 4))];
        bf16x8 kB = *(const bf16x8*)&KV[rb * 256 + (off ^ ((rb & 7) << 4))];
        bf16x8 t0, t1;
#pragma unroll
        for (int j = 0; j < 8; ++j) {
            t0[j] = f2b(b2f(qf[0][kt][j]) - b2f(kA[j]) + b2f(pA[j]));
            t1[j] = f2b(b2f(qf[1][kt][j]) - b2f(kB[j]) + b2f(pB[j]));
        }
#pragma unroll
        for (int nt = 0; nt < 8; ++nt) {
            bf16x8 bv = *(const bf16x8*)(pk_a1 + (size_t)((kt * 8 + nt) * 64 + l) * 8);
            acc[0][nt] = MFMA_B16(t0, bv, acc[0][nt]);
            acc[1][nt] = MFMA_B16(t1, bv, acc[1][nt]);
        }
    }
    // all K reads retired -> V DMA into same slots (hidden under relu+A2)
    asm volatile("s_waitcnt lgkmcnt(0)" ::: "memory");
#pragma unroll
    for (int it = 0; it < 8; ++it) {
        int g = __shfl(g_reg, it * 4 + (l >> 4));
        int srcch = cl ^ ((it * 4 + (l >> 4)) & 7);
        gload_lds16(vg + (size_t)g * 128 + srcch * 8, KV + it * 1024);
    }
    // relu(+at_b1) -> WK (overwrites pe copy; pe_ regs keep f32 values)
#pragma unroll
    for (int nt = 0; nt < 8; ++nt) {
        float bv = at_b1[nt * 16 + cl];
        int col = nt * 16 + cl;
#pragma unroll
        for (int mt = 0; mt < 2; ++mt)
#pragma unroll
            for (int j = 0; j < 4; ++j) {
                int lr = mt * 16 + (l >> 4) * 4 + j;
                *(short*)&WK[lr * 256 + ((col * 2) ^ ((lr & 7) << 4))] = f2b(fmaxf(acc[mt][nt][j] + bv, 0.f));
            }
    }
    // A2 GEMM
#pragma unroll
    for (int mt = 0; mt < 2; mt++)
#pragma unroll
        for (int nt = 0; nt < 8; nt++) acc[mt][nt] = (f32x4){0.f, 0.f, 0.f, 0.f};
#pragma unroll
    for (int kt = 0; kt < 4; ++kt) {
        int ra = (l & 15), rb = 16 + (l & 15);
        int off = kt * 64 + (l >> 4) * 16;
        bf16x8 a0 = *(const bf16x8*)&WK[ra * 256 + (off ^ ((ra & 7) << 4))];
        bf16x8 a1 = *(const bf16x8*)&WK[rb * 256 + (off ^ ((rb & 7) << 4))];
#pragma unroll
        for (int nt = 0; nt < 8; ++nt) {
            bf16x8 bv = *(const bf16x8*)(pk_a2 + (size_t)((kt * 8 + nt) * 64 + l) * 8);
            acc[0][nt] = MFMA_B16(a0, bv, acc[0][nt]);
            acc[1][nt] = MFMA_B16(a1, bv, acc[1][nt]);
        }
    }
    // wait V; per-channel softmax over K + weighted (v+pe) sum
    asm volatile("s_waitcnt vmcnt(0)" ::: "memory");
    const float scale = 0.08838834764831845f;
#pragma unroll
    for (int mt = 0; mt < 2; ++mt) {
        int P = p0 + w * 2 + mt;
#pragma unroll
        for (int nt = 0; nt < 8; ++nt) {
            int col = nt * 16 + cl;
            float bv = at_b2[col];
            float vv[4];
#pragma unroll
            for (int j = 0; j < 4; ++j) vv[j] = (acc[mt][nt][j] + bv) * scale;
            float m = fmaxf(fmaxf(vv[0], vv[1]), fmaxf(vv[2], vv[3]));
            m = fmaxf(m, __shfl_xor(m, 16));
            m = fmaxf(m, __shfl_xor(m, 32));
            float ee[4], es = 0.f;
#pragma unroll
            for (int j = 0; j < 4; ++j) { ee[j] = __expf(vv[j] - m); es += ee[j]; }
            es += __shfl_xor(es, 16);
            es += __shfl_xor(es, 32);
            float o = 0.f;
#pragma unroll
            for (int j = 0; j < 4; ++j) {
                int lr = mt * 16 + (l >> 4) * 4 + j;
                float vvv = b2f(*(const short*)&KV[lr * 256 + ((col * 2) ^ ((lr & 7) << 4))]);
                o += ee[j] * (vvv + pe_[mt][nt][j]);
            }
            o += __shfl_xor(o, 16);
            o += __shfl_xor(o, 32);
            if (l < 16) res1[(size_t)P * 128 + col] = o / es;
        }
    }
}

// ---------------- final head (f32 VALU) ----------------
__global__ __launch_bounds__(256) void k_head(const float* __restrict__ res1, const float* __restrict__ feat,
                                              const float* __restrict__ ag_w, const float* __restrict__ ag_b,
                                              const float* __restrict__ mlp_w1, const float* __restrict__ mlp_b1,
                                              const float* __restrict__ mlp_w2, const float* __restrict__ mlp_b2,
                                              float* __restrict__ out) {
    __shared__ __align__(16) float rs[64][128];
    __shared__ __align__(16) float r1s[64][64];
    int tid = threadIdx.x;
    int i0 = blockIdx.x * 64;
    for (int e = tid; e < 64 * 128; e += 256) rs[e >> 7][e & 127] = res1[(size_t)i0 * 128 + e];
    __syncthreads();
    {
        int d = tid & 63, rg = tid >> 6;
        float acc[16];
#pragma unroll
        for (int i = 0; i < 16; i++) acc[i] = 0.0f;
        for (int c4 = 0; c4 < 32; ++c4) {
            int c = c4 * 4;
            float w0 = ag_w[c * 64 + d], w1 = ag_w[(c + 1) * 64 + d];
            float w2 = ag_w[(c + 2) * 64 + d], w3 = ag_w[(c + 3) * 64 + d];
#pragma unroll
            for (int i = 0; i < 16; i++) {
                float4 f = *(const float4*)&rs[rg * 16 + i][c];
                acc[i] += f.x * w0 + f.y * w1 + f.z * w2 + f.w * w3;
            }
        }
        float bb = ag_b[d];
#pragma unroll
        for (int i = 0; i < 16; i++) {
            int pp = rg * 16 + i;
            r1s[pp][d] = acc[i] + bb + feat[(size_t)(i0 + pp) * 64 + d];
        }
    }
    __syncthreads();
    {
        int d = tid & 127, rg = tid >> 7;
        float acc[32];
#pragma unroll
        for (int i = 0; i < 32; i++) acc[i] = 0.0f;
        for (int c4 = 0; c4 < 16; ++c4) {
            int c = c4 * 4;
            float w0 = mlp_w1[c * 128 + d], w1 = mlp_w1[(c + 1) * 128 + d];
            float w2 = mlp_w1[(c + 2) * 128 + d], w3 = mlp_w1[(c + 3) * 128 + d];
#pragma unroll
            for (int i = 0; i < 32; i++) {
                float4 f = *(const float4*)&r1s[rg * 32 + i][c];
                acc[i] += f.x * w0 + f.y * w1 + f.z * w2 + f.w * w3;
            }
        }
        float bb = mlp_b1[d];
#pragma unroll
        for (int i = 0; i < 32; i++) {
            float x = acc[i] + bb;
            rs[rg * 32 + i][d] = 0.5f * x * (1.0f + erff(x * 0.70710678118654752f));
        }
    }
    __syncthreads();
    {
        int d = tid & 63, rg = tid >> 6;
        float acc[16];
#pragma unroll
        for (int i = 0; i < 16; i++) acc[i] = 0.0f;
        for (int c4 = 0; c4 < 32; ++c4) {
            int c = c4 * 4;
            float w0 = mlp_w2[c * 64 + d], w1 = mlp_w2[(c + 1) * 64 + d];
            float w2 = mlp_w2[(c + 2) * 64 + d], w3 = mlp_w2[(c + 3) * 64 + d];
#pragma unroll
            for (int i = 0; i < 16; i++) {
                float4 f = *(const float4*)&rs[rg * 16 + i][c];
                acc[i] += f.x * w0 + f.y * w1 + f.z * w2 + f.w * w3;
            }
        }
        float bb = mlp_b2[d];
#pragma unroll
        for (int i = 0; i < 16; i++) {
            int pp = rg * 16 + i;
            out[(size_t)(i0 + pp) * 64 + d] = acc[i] + bb + feat[(size_t)(i0 + pp) * 64 + d];
        }
    }
}

extern "C" void kernel_launch(void* const* d_in, const int* in_sizes, int n_in,
                              void* d_out, int out_size, void* d_ws, size_t ws_size,
                              hipStream_t stream) {
    const float* xyzp = (const float*)d_in[0];
    const float* features = (const float*)d_in[1];
    const float* ln_g = (const float*)d_in[2];
    const float* ln_b = (const float*)d_in[3];
    const float* W1 = (const float*)d_in[4];
    const float* b1 = (const float*)d_in[5];
    const float* W2 = (const float*)d_in[6];
    const float* pe_w1 = (const float*)d_in[7];
    const float* pe_b1 = (const float*)d_in[8];
    const float* pe_w2 = (const float*)d_in[9];
    const float* pe_b2 = (const float*)d_in[10];
    const float* at_w1 = (const float*)d_in[11];
    const float* at_b1 = (const float*)d_in[12];
    const float* at_w2 = (const float*)d_in[13];
    const float* at_b2 = (const float*)d_in[14];
    const float* ag_w = (const float*)d_in[15];
    const float* ag_b = (const float*)d_in[16];
    const float* mlp_w1 = (const float*)d_in[17];
    const float* mlp_b1 = (const float*)d_in[18];
    const float* mlp_w2 = (const float*)d_in[19];
    const float* mlp_b2 = (const float*)d_in[20];
    float* out = (float*)d_out;

    char* w = (char*)d_ws;
    auto alloc = [&](size_t bytes) { char* pp = w; w += (bytes + 255) & ~(size_t)255; return pp; };
    int* grid = (int*)alloc((size_t)BB * GS * GS * 4);
    short* zero256 = (short*)alloc(256);
    int* cxy = (int*)alloc((size_t)BB * NN * 4);
    unsigned* part = (unsigned*)alloc((size_t)BB * NN * NC * KNN * 4);
    int* idxb = (int*)alloc((size_t)BB * NN * KNN * 4);
    float4* relg = (float4*)alloc((size_t)BB * NN * KNN * 16);
    short* sp_bf = (short*)alloc((size_t)BB * NN * 128 * 2);
    short* h1_bf = (short*)alloc((size_t)BB * NN * HID * 2);
    short* qg = (short*)alloc((size_t)BB * NN * HID * 2);
    short* kg = (short*)alloc((size_t)BB * NN * HID * 2);
    short* vg = (short*)alloc((size_t)BB * NN * HID * 2);
    float* res1 = (float*)alloc((size_t)BB * NN * HID * 4);
    short* pk_pe2 = (short*)alloc((size_t)PK128_SZ * 2);
    short* pk_a1 = (short*)alloc((size_t)PK128_SZ * 2);
    short* pk_a2 = (short*)alloc((size_t)PK128_SZ * 2);
    short* pk_w1 = (short*)alloc((size_t)PKW1_SZ * 2);
    short* pk_w2 = (short*)alloc((size_t)PKW2_SZ * 2);

    k_grid_init<<<(BB * GS * GS + 128 + 255) / 256, 256, 0, stream>>>(grid, zero256);
    k_scatter<<<(BB * NN + 255) / 256, 256, 0, stream>>>(xyzp, grid, cxy);
    k_pack<<<(3 * PK128_SZ + PKW1_SZ + PKW2_SZ + 255) / 256, 256, 0, stream>>>(
        pe_w2, at_w1, at_w2, W1, W2, pk_pe2, pk_a1, pk_a2, pk_w1, pk_w2);
    k_knn_part<<<BB * (NN / 256) * NC, 256, 0, stream>>>(cxy, part);
    k_knn_merge<<<BB * NN / 64, 64, 0, stream>>>(part, idxb);
    k_prep<<<(BB * NN * KNN + 255) / 256, 256, 0, stream>>>(xyzp, idxb, relg);
    k_sp<<<(BB * NN + 255) / 256, 256, 0, stream>>>(xyzp, features, ln_g, ln_b, sp_bf);
    k_conv1<<<BB * NN / 64, 256, 0, stream>>>(grid, cxy, sp_bf, b1, pk_w1, zero256, h1_bf);
    k_conv2<<<(BB * NN / 64) * 3, 256, 0, stream>>>(grid, cxy, h1_bf, pk_w2, zero256, qg, kg, vg);
    k_attn<<<BB * NN / 8, 256, 0, stream>>>(relg, qg, kg, vg, pe_w1, pe_b1, pe_b2, at_b1, at_b2,
                                            pk_pe2, pk_a1, pk_a2, res1);
    k_head<<<BB * NN / 64, 256, 0, stream>>>(res1, features, ag_w, ag_b, mlp_w1, mlp_b1, mlp_w2, mlp_b2, out);
}

// Round 5
// 393.282 us; speedup vs baseline: 3.1396x; 1.1087x over previous
//
#include <hip/hip_runtime.h>
#include <math.h>

#define BB 4
#define NN 4096
#define FEAT 64
#define HID 128
#define KNN 16
#define GS 258
#define CIN 66
#define NC 8
#define CHUNK (NN / NC)

typedef __attribute__((ext_vector_type(8))) short bf16x8;
typedef __attribute__((ext_vector_type(4))) float f32x4;
#define MFMA_B16(a, b, c) __builtin_amdgcn_mfma_f32_16x16x32_bf16(a, b, c, 0, 0, 0)

__device__ __forceinline__ short f2b(float f) {
    unsigned u = __builtin_bit_cast(unsigned, f);
    u = (u + 0x7FFFu + ((u >> 16) & 1u)) >> 16;
    return (short)u;
}
__device__ __forceinline__ float b2f(short s) {
    return __builtin_bit_cast(float, ((unsigned)(unsigned short)s) << 16);
}
__device__ __forceinline__ void gload_lds16(const void* g, void* lds) {
    __builtin_amdgcn_global_load_lds((const __attribute__((address_space(1))) unsigned int*)g,
                                     (__attribute__((address_space(3))) unsigned int*)lds, 16, 0, 0);
}

// ---------------- grid build (+ zero page) ----------------
__global__ void k_grid_init(int* grid, short* zero256) {
    int i = blockIdx.x * 256 + threadIdx.x;
    if (i < BB * GS * GS) grid[i] = -1;
    int z = i - BB * GS * GS;
    if (z >= 0 && z < 128) zero256[z] = 0;
}

__global__ void k_scatter(const float* __restrict__ xyzp, int* __restrict__ grid, int* __restrict__ cxy) {
    int i = blockIdx.x * 256 + threadIdx.x;
    if (i >= BB * NN) return;
    int b = i / NN, n = i % NN;
    float x = xyzp[(size_t)i * 4 + 0], y = xyzp[(size_t)i * 4 + 1];
    int cx = __float2int_rn(x * 256.0f);
    int cy = __float2int_rn(y * 256.0f);
    cxy[i] = cx | (cy << 8);
    grid[b * GS * GS + (cy + 1) * GS + (cx + 1)] = n;
}

// ---------------- exact KNN (integer d2, tie-break lower index) ----------------
__global__ __launch_bounds__(256) void k_knn_part(const int* __restrict__ cxy, unsigned* __restrict__ part) {
    int bid = blockIdx.x;
    int ch = bid % NC; bid /= NC;
    int qb = bid % (NN / 256);
    int b = bid / (NN / 256);
    int n = qb * 256 + threadIdx.x;
    __shared__ int sc[CHUNK];
    for (int t = threadIdx.x; t < CHUNK; t += 256) sc[t] = cxy[b * NN + ch * CHUNK + t];
    __syncthreads();
    int me = cxy[b * NN + n];
    int mx = me & 255, my = (me >> 8) & 255;
    unsigned a[KNN];
#pragma unroll
    for (int j = 0; j < KNN; j++) a[j] = 0xFFFFFFFFu;
    for (int t = 0; t < CHUNK; ++t) {
        int c = sc[t];
        int dx = mx - (c & 255), dy = my - ((c >> 8) & 255);
        unsigned d2 = (unsigned)(dx * dx + dy * dy);
        unsigned key = (d2 << 12) | (unsigned)(ch * CHUNK + t);
        if (key < a[KNN - 1]) {
#pragma unroll
            for (int j = KNN - 1; j >= 1; --j) {
                unsigned prev = a[j - 1];
                a[j] = (prev > key) ? prev : ((a[j] > key) ? key : a[j]);
            }
            a[0] = a[0] < key ? a[0] : key;
        }
    }
    unsigned* dst = part + ((size_t)(b * NN + n) * NC + ch) * KNN;
#pragma unroll
    for (int j = 0; j < KNN; j++) dst[j] = a[j];
}

__global__ __launch_bounds__(256) void k_knn_merge(const unsigned* __restrict__ part, int* __restrict__ idxo) {
    int q = blockIdx.x * 256 + threadIdx.x;
    if (q >= BB * NN) return;
    unsigned a[KNN];
#pragma unroll
    for (int j = 0; j < KNN; j++) a[j] = 0xFFFFFFFFu;
    for (int ch = 0; ch < NC; ++ch) {
#pragma unroll
        for (int j = 0; j < KNN; j++) {
            unsigned key = part[((size_t)q * NC + ch) * KNN + j];
            if (key < a[KNN - 1]) {
#pragma unroll
                for (int t = KNN - 1; t >= 1; --t) {
                    unsigned prev = a[t - 1];
                    a[t] = (prev > key) ? prev : ((a[t] > key) ? key : a[t]);
                }
                a[0] = a[0] < key ? a[0] : key;
            }
        }
    }
#pragma unroll
    for (int j = 0; j < KNN; j++) idxo[(size_t)q * KNN + j] = (int)(a[j] & 4095u);
}

// ---------------- rel/g table: relg[i] = {x-xg, y-yg, p-pg, g} ----------------
__global__ __launch_bounds__(256) void k_prep(const float* __restrict__ xyzp, const int* __restrict__ idxb,
                                              float4* __restrict__ relg) {
    int i = blockIdx.x * 256 + threadIdx.x;
    if (i >= BB * NN * KNN) return;
    int P = i >> 4;
    int base = P & ~(NN - 1);
    int g = base + idxb[i];
    float4 a = *(const float4*)(xyzp + (size_t)P * 4);
    float4 bq = *(const float4*)(xyzp + (size_t)g * 4);
    float4 o;
    o.x = a.x - bq.x; o.y = a.y - bq.y; o.z = a.w - bq.w;
    o.w = __int_as_float(g);
    relg[i] = o;
}

// ---------------- weight pre-pack into bf16 MFMA B-fragments ----------------
#define PK128_SZ (4 * 8 * 512)
#define PKW1_SZ (9 * 3 * 8 * 512)
#define PKW2_SZ (9 * 4 * 24 * 512)

__global__ __launch_bounds__(256) void k_pack(const float* __restrict__ pe_w2, const float* __restrict__ at_w1,
                                              const float* __restrict__ at_w2, const float* __restrict__ W1,
                                              const float* __restrict__ W2,
                                              short* __restrict__ pk_pe2, short* __restrict__ pk_a1,
                                              short* __restrict__ pk_a2, short* __restrict__ pk_w1,
                                              short* __restrict__ pk_w2) {
    int i = blockIdx.x * 256 + threadIdx.x;
    if (i < 3 * PK128_SZ) {
        int seg = i / PK128_SZ, r = i % PK128_SZ;
        int f = r / 512, q = r % 512;
        int lane = q / 8, j = q % 8;
        int kt = f / 8, nt = f % 8;
        int k = kt * 32 + (lane >> 4) * 8 + j, n = nt * 16 + (lane & 15);
        const float* W = (seg == 0) ? pe_w2 : (seg == 1) ? at_w1 : at_w2;
        short* dst = (seg == 0) ? pk_pe2 : (seg == 1) ? pk_a1 : pk_a2;
        dst[r] = f2b(W[k * 128 + n]);
        return;
    }
    i -= 3 * PK128_SZ;
    if (i < PKW1_SZ) {
        int f = i / 512, q = i % 512;
        int lane = q / 8, j = q % 8;
        int tap = f / 24, rem = f % 24;
        int kt = rem / 8, nt = rem % 8;
        int k = kt * 32 + (lane >> 4) * 8 + j, n = nt * 16 + (lane & 15);
        pk_w1[i] = (k < CIN) ? f2b(W1[(tap * CIN + k) * 128 + n]) : (short)0;
        return;
    }
    i -= PKW1_SZ;
    if (i < PKW2_SZ) {
        int f = i / 512, q = i % 512;
        int lane = q / 8, j = q % 8;
        int tap = f / 96, rem = f % 96;
        int kt = rem / 24, nt = rem % 24;
        int k = kt * 32 + (lane >> 4) * 8 + j, n = nt * 16 + (lane & 15);
        pk_w2[i] = f2b(W2[((size_t)(tap * 128 + k)) * 384 + n]);
    }
}

// ---------------- fold: Wf = pe_w2 @ at_w1 (packed B-frags), cf = pe_b2@at_w1 + at_b1 ----------------
__global__ __launch_bounds__(256) void k_fold(const float* __restrict__ pe_w2, const float* __restrict__ at_w1,
                                              const float* __restrict__ pe_b2, const float* __restrict__ at_b1,
                                              short* __restrict__ pk_wf, float* __restrict__ cf) {
    int bid = blockIdx.x;
    if (bid == 64) {
        int j = threadIdx.x;
        if (j < 128) {
            float acc = at_b1[j];
            for (int m = 0; m < 128; ++m) acc += pe_b2[m] * at_w1[m * 128 + j];
            cf[j] = acc;
        }
        return;
    }
    int idx = bid * 256 + threadIdx.x;
    int i = idx >> 7, j = idx & 127;
    float acc = 0.f;
    for (int m = 0; m < 128; ++m) acc += pe_w2[i * 128 + m] * at_w1[m * 128 + j];
    int lane = (((i >> 3) & 3) << 4) | (j & 15);
    int dst = ((i >> 5) * 8 + (j >> 4)) * 512 + lane * 8 + (i & 7);
    pk_wf[dst] = f2b(acc);
}

// ---------------- sp = LayerNorm(...) -> bf16, padded to 128 cols ----------------
__global__ __launch_bounds__(256) void k_sp(const float* __restrict__ xyzp, const float* __restrict__ feat,
                                            const float* __restrict__ ln_g, const float* __restrict__ ln_b,
                                            short* __restrict__ sp_bf) {
    int i = blockIdx.x * 256 + threadIdx.x;
    if (i >= BB * NN) return;
    float v[CIN];
    float p = xyzp[(size_t)i * 4 + 3];
    float pn = (p - 0.5f) * 2.0f;
    v[0] = fminf(fmaxf(pn, 0.0f), 1.0f);
    v[1] = -fminf(fmaxf(pn, -1.0f), 0.0f);
    const float4* f4 = (const float4*)(feat + (size_t)i * FEAT);
#pragma unroll
    for (int j = 0; j < FEAT / 4; j++) {
        float4 t = f4[j];
        v[2 + 4 * j] = t.x; v[3 + 4 * j] = t.y; v[4 + 4 * j] = t.z; v[5 + 4 * j] = t.w;
    }
    float s = 0.0f;
#pragma unroll
    for (int j = 0; j < CIN; j++) s += v[j];
    float mu = s / (float)CIN;
    float vs = 0.0f;
#pragma unroll
    for (int j = 0; j < CIN; j++) { float d = v[j] - mu; vs += d * d; }
    float inv = 1.0f / sqrtf(vs / (float)CIN + 1e-5f);
    unsigned o2[64];
#pragma unroll
    for (int j = 0; j < 33; j++) {
        float a = (v[2 * j] - mu) * inv * ln_g[2 * j] + ln_b[2 * j];
        float bqq = (2 * j + 1 < CIN) ? ((v[2 * j + 1] - mu) * inv * ln_g[2 * j + 1] + ln_b[2 * j + 1]) : 0.f;
        o2[j] = (unsigned)(unsigned short)f2b(a) | (((unsigned)(unsigned short)f2b(bqq)) << 16);
    }
#pragma unroll
    for (int j = 33; j < 64; j++) o2[j] = 0;
    int4* o = (int4*)(sp_bf + (size_t)i * 128);
#pragma unroll
    for (int t = 0; t < 16; t++) o[t] = make_int4(o2[4 * t], o2[4 * t + 1], o2[4 * t + 2], o2[4 * t + 3]);
}

// ---------------- conv1 (MFMA, 64-row blocks, DMA double-buffered) ----------------
__global__ __launch_bounds__(256) void k_conv1(const int* __restrict__ grid, const int* __restrict__ cxy,
                                               const short* __restrict__ sp_bf, const float* __restrict__ b1,
                                               const short* __restrict__ pk_w1, const short* __restrict__ zero256,
                                               short* __restrict__ h1_bf) {
    __shared__ int sj[9][64];
    __shared__ __align__(16) char sb[2][64 * 256];
    int row0 = blockIdx.x * 64;
    int b = row0 / NN;
    int tid = threadIdx.x;
    int w = tid >> 6, l = tid & 63, cl = l & 15;
    for (int e = tid; e < 9 * 64; e += 256) {
        int k = e / 64, p = e % 64;
        int me = cxy[row0 + p];
        sj[k][p] = grid[b * GS * GS + (((me >> 8) & 255) + k / 3) * GS + ((me & 255) + k % 3)];
    }
    __syncthreads();
    f32x4 acc[4][2];
#pragma unroll
    for (int m = 0; m < 4; m++)
#pragma unroll
        for (int nt = 0; nt < 2; nt++) acc[m][nt] = (f32x4){0.f, 0.f, 0.f, 0.f};

#define STAGE1(bufp, tap)                                                                      \
    {                                                                                          \
        _Pragma("unroll") for (int i = 0; i < 4; ++i) {                                        \
            int row = w * 16 + i * 4 + (l >> 4);                                               \
            int j = sj[tap][row];                                                              \
            int srcch = cl ^ (row & 7);                                                        \
            const short* src = (j >= 0) ? (sp_bf + ((size_t)(b * NN + j) * 128 + srcch * 8))   \
                                        : (zero256 + srcch * 8);                               \
            gload_lds16(src, (bufp) + (w * 16 + i * 4) * 256);                                 \
        }                                                                                      \
    }
    STAGE1(&sb[0][0], 0);
    asm volatile("s_waitcnt vmcnt(0)" ::: "memory");
    __syncthreads();
    int cur = 0;
    for (int tap = 0; tap < 9; ++tap) {
        if (tap < 8) STAGE1(&sb[cur ^ 1][0], tap + 1);
        const char* base = &sb[cur][0];
#pragma unroll
        for (int kt = 0; kt < 3; ++kt) {
            bf16x8 a[4];
#pragma unroll
            for (int m = 0; m < 4; ++m) {
                int row = m * 16 + (l & 15);
                a[m] = *(const bf16x8*)&base[row * 256 + ((kt * 64 + (l >> 4) * 16) ^ ((row & 7) << 4))];
            }
#pragma unroll
            for (int nt = 0; nt < 2; ++nt) {
                bf16x8 bv = *(const bf16x8*)(pk_w1 + (size_t)(((tap * 3 + kt) * 8 + w * 2 + nt) * 64 + l) * 8);
#pragma unroll
                for (int m = 0; m < 4; ++m) acc[m][nt] = MFMA_B16(a[m], bv, acc[m][nt]);
            }
        }
        asm volatile("s_waitcnt vmcnt(0)" ::: "memory");
        __syncthreads();
        cur ^= 1;
    }
#pragma unroll
    for (int nt = 0; nt < 2; ++nt) {
        int col = (w * 2 + nt) * 16 + cl;
        float bb = b1[col];
#pragma unroll
        for (int m = 0; m < 4; ++m)
#pragma unroll
            for (int j = 0; j < 4; ++j) {
                int row = row0 + m * 16 + (l >> 4) * 4 + j;
                h1_bf[(size_t)row * 128 + col] = f2b(acc[m][nt][j] + bb);
            }
    }
}

// ---------------- conv2 (MFMA, 64-row blocks, DMA double-buffered) ----------------
__global__ __launch_bounds__(256) void k_conv2(const int* __restrict__ grid, const int* __restrict__ cxy,
                                               const short* __restrict__ h1_bf, const short* __restrict__ pk_w2,
                                               const short* __restrict__ zero256,
                                               short* __restrict__ qg, short* __restrict__ kg, short* __restrict__ vg) {
    __shared__ int sj[9][64];
    __shared__ __align__(16) char sb[2][64 * 256];
    int bid = blockIdx.x;
    int nb = bid % 3, mb = bid / 3;
    int row0 = mb * 64;
    int b = row0 / NN;
    int tid = threadIdx.x;
    int w = tid >> 6, l = tid & 63, cl = l & 15;
    for (int e = tid; e < 9 * 64; e += 256) {
        int k = e / 64, p = e % 64;
        int me = cxy[row0 + p];
        sj[k][p] = grid[b * GS * GS + (((me >> 8) & 255) + k / 3) * GS + ((me & 255) + k % 3)];
    }
    __syncthreads();
    f32x4 acc[4][2];
#pragma unroll
    for (int m = 0; m < 4; m++)
#pragma unroll
        for (int nt = 0; nt < 2; nt++) acc[m][nt] = (f32x4){0.f, 0.f, 0.f, 0.f};

#define STAGE2(bufp, tap)                                                                      \
    {                                                                                          \
        _Pragma("unroll") for (int i = 0; i < 4; ++i) {                                        \
            int row = w * 16 + i * 4 + (l >> 4);                                               \
            int j = sj[tap][row];                                                              \
            int srcch = cl ^ (row & 7);                                                        \
            const short* src = (j >= 0) ? (h1_bf + ((size_t)(b * NN + j) * 128 + srcch * 8))   \
                                        : (zero256 + srcch * 8);                               \
            gload_lds16(src, (bufp) + (w * 16 + i * 4) * 256);                                 \
        }                                                                                      \
    }
    STAGE2(&sb[0][0], 0);
    asm volatile("s_waitcnt vmcnt(0)" ::: "memory");
    __syncthreads();
    int cur = 0;
    for (int tap = 0; tap < 9; ++tap) {
        if (tap < 8) STAGE2(&sb[cur ^ 1][0], tap + 1);
        const char* base = &sb[cur][0];
#pragma unroll
        for (int kt = 0; kt < 4; ++kt) {
            bf16x8 a[4];
#pragma unroll
            for (int m = 0; m < 4; ++m) {
                int row = m * 16 + (l & 15);
                a[m] = *(const bf16x8*)&base[row * 256 + ((kt * 64 + (l >> 4) * 16) ^ ((row & 7) << 4))];
            }
#pragma unroll
            for (int nt = 0; nt < 2; ++nt) {
                bf16x8 bv = *(const bf16x8*)(pk_w2 + (size_t)(((tap * 4 + kt) * 24 + nb * 8 + w * 2 + nt) * 64 + l) * 8);
#pragma unroll
                for (int m = 0; m < 4; ++m) acc[m][nt] = MFMA_B16(a[m], bv, acc[m][nt]);
            }
        }
        asm volatile("s_waitcnt vmcnt(0)" ::: "memory");
        __syncthreads();
        cur ^= 1;
    }
#pragma unroll
    for (int nt = 0; nt < 2; ++nt) {
        int col = nb * 128 + (w * 2 + nt) * 16 + cl;
        int s = col % 3, dd = col / 3;
        short* dst = (s == 0) ? qg : (s == 1) ? kg : vg;
#pragma unroll
        for (int m = 0; m < 4; ++m)
#pragma unroll
            for (int j = 0; j < 4; ++j) {
                int row = row0 + m * 16 + (l >> 4) * 4 + j;
                dst[(size_t)row * 128 + dd] = f2b(acc[m][nt][j]);
            }
    }
}

// ---------------- q1/k1 dense projection: S @ at_w1 (+cf for q) -> bf16 ----------------
__global__ __launch_bounds__(256) void k_qk1(const short* __restrict__ qg, const short* __restrict__ kg,
                                             const short* __restrict__ pk_a1, const float* __restrict__ cf,
                                             short* __restrict__ q1, short* __restrict__ k1) {
    __shared__ __align__(16) char sb[64 * 256];
    int bid = blockIdx.x;
    int qmode = (bid < 256);
    int row0 = (bid & 255) * 64;
    const short* S = qmode ? qg : kg;
    short* O = qmode ? q1 : k1;
    int tid = threadIdx.x;
    int w = tid >> 6, l = tid & 63, cl = l & 15;
    for (int e = tid; e < 1024; e += 256) {
        int row = e >> 4, sl = e & 15;
        gload_lds16(S + ((size_t)(row0 + row) * 128 + (sl ^ (row & 7)) * 8), &sb[e * 16]);
    }
    asm volatile("s_waitcnt vmcnt(0)" ::: "memory");
    __syncthreads();
    f32x4 acc[4][2];
#pragma unroll
    for (int m = 0; m < 4; m++)
#pragma unroll
        for (int nt = 0; nt < 2; nt++) acc[m][nt] = (f32x4){0.f, 0.f, 0.f, 0.f};
#pragma unroll
    for (int kt = 0; kt < 4; ++kt) {
        bf16x8 a[4];
#pragma unroll
        for (int m = 0; m < 4; ++m) {
            int row = m * 16 + (l & 15);
            a[m] = *(const bf16x8*)&sb[row * 256 + ((kt * 64 + (l >> 4) * 16) ^ ((row & 7) << 4))];
        }
#pragma unroll
        for (int nt = 0; nt < 2; ++nt) {
            bf16x8 bv = *(const bf16x8*)(pk_a1 + (size_t)((kt * 8 + w * 2 + nt) * 64 + l) * 8);
#pragma unroll
            for (int m = 0; m < 4; ++m) acc[m][nt] = MFMA_B16(a[m], bv, acc[m][nt]);
        }
    }
#pragma unroll
    for (int nt = 0; nt < 2; ++nt) {
        int col = (w * 2 + nt) * 16 + cl;
        float cv = qmode ? cf[col] : 0.f;
#pragma unroll
        for (int m = 0; m < 4; ++m)
#pragma unroll
            for (int j = 0; j < 4; ++j) {
                int row = row0 + m * 16 + (l >> 4) * 4 + j;
                O[(size_t)row * 128 + col] = f2b(acc[m][nt][j] + cv);
            }
    }
}

// ---------------- fused attention (folded at_w1; no q/k/t path) ----------------
__global__ __launch_bounds__(256) void k_attn(const float4* __restrict__ relg,
                                              const short* __restrict__ q1g, const short* __restrict__ k1g,
                                              const short* __restrict__ vg,
                                              const float* __restrict__ pe_w1, const float* __restrict__ pe_b1,
                                              const float* __restrict__ pe_b2, const float* __restrict__ at_b2,
                                              const short* __restrict__ pk_pe2, const short* __restrict__ pk_wf,
                                              const short* __restrict__ pk_a2, float* __restrict__ res1) {
    __shared__ __align__(16) char s_work[4 * 8192];  // per-wave 32 rows x 256B: hidden -> relu
    __shared__ __align__(16) char s_kv[4 * 8192];    // per-wave 32 rows x 256B: k1 -> v
    __shared__ float4 s_rel[128];
    int tid = threadIdx.x;
    int w = tid >> 6, l = tid & 63;
    int r0 = w * 32;
    int p0 = blockIdx.x * 8;
    int cl = l & 15;
    char* WK = s_work + w * 8192;
    char* KV = s_kv + w * 8192;

    int g_reg = 0;
    if (l < 32) {
        float4 f4 = relg[(size_t)p0 * 16 + r0 + l];
        s_rel[r0 + l] = f4;
        g_reg = __float_as_int(f4.w);
    }
    // K1 gather DMA (slot-preswizzled source)
#pragma unroll
    for (int it = 0; it < 8; ++it) {
        int g = __shfl(g_reg, it * 4 + (l >> 4));
        int srcch = cl ^ ((it * 4 + (l >> 4)) & 7);
        gload_lds16(k1g + (size_t)g * 128 + srcch * 8, KV + it * 1024);
    }
    // q1 prefetch (C-layout scalar u16)
    unsigned short q1pre[2][8];
#pragma unroll
    for (int mt = 0; mt < 2; ++mt) {
        int P = p0 + w * 2 + mt;
#pragma unroll
        for (int nt = 0; nt < 8; ++nt)
            q1pre[mt][nt] = *(const unsigned short*)((const unsigned short*)q1g + (size_t)P * 128 + nt * 16 + cl);
    }
    // PE1: hidden = relu(rel @ pe_w1 + pe_b1) -> WK (hides DMA)
    {
        int c0 = 2 * l;
        float wa0 = pe_w1[c0], wa1 = pe_w1[c0 + 1];
        float wb0 = pe_w1[128 + c0], wb1 = pe_w1[129 + c0];
        float wc0 = pe_w1[256 + c0], wc1 = pe_w1[257 + c0];
        float ba0 = pe_b1[c0], ba1 = pe_b1[c0 + 1];
        for (int lr = 0; lr < 32; ++lr) {
            float4 rel = s_rel[r0 + lr];
            float h0 = fmaxf(rel.x * wa0 + rel.y * wb0 + rel.z * wc0 + ba0, 0.f);
            float h1v = fmaxf(rel.x * wa1 + rel.y * wb1 + rel.z * wc1 + ba1, 0.f);
            unsigned pk = (unsigned)(unsigned short)f2b(h0) | (((unsigned)(unsigned short)f2b(h1v)) << 16);
            *(unsigned*)&WK[lr * 256 + ((4 * l) ^ ((lr & 7) << 4))] = pk;
        }
    }
    // GEMM-pe: pe = hidden @ pe_w2 + pe_b2 -> packed bf16 regs
    unsigned pe_pk[2][8][2];
    {
        f32x4 pacc[2][8];
#pragma unroll
        for (int mt = 0; mt < 2; mt++)
#pragma unroll
            for (int nt = 0; nt < 8; nt++) pacc[mt][nt] = (f32x4){0.f, 0.f, 0.f, 0.f};
#pragma unroll
        for (int kt = 0; kt < 4; ++kt) {
            int ra = (l & 15), rb = 16 + (l & 15);
            int off = kt * 64 + (l >> 4) * 16;
            bf16x8 a0 = *(const bf16x8*)&WK[ra * 256 + (off ^ ((ra & 7) << 4))];
            bf16x8 a1 = *(const bf16x8*)&WK[rb * 256 + (off ^ ((rb & 7) << 4))];
#pragma unroll
            for (int nt = 0; nt < 8; ++nt) {
                bf16x8 bv = *(const bf16x8*)(pk_pe2 + (size_t)((kt * 8 + nt) * 64 + l) * 8);
                pacc[0][nt] = MFMA_B16(a0, bv, pacc[0][nt]);
                pacc[1][nt] = MFMA_B16(a1, bv, pacc[1][nt]);
            }
        }
#pragma unroll
        for (int nt = 0; nt < 8; ++nt) {
            float b2v = pe_b2[nt * 16 + cl];
#pragma unroll
            for (int mt = 0; mt < 2; ++mt) {
                float p0v = pacc[mt][nt][0] + b2v, p1v = pacc[mt][nt][1] + b2v;
                float p2v = pacc[mt][nt][2] + b2v, p3v = pacc[mt][nt][3] + b2v;
                pe_pk[mt][nt][0] = (unsigned)(unsigned short)f2b(p0v) | (((unsigned)(unsigned short)f2b(p1v)) << 16);
                pe_pk[mt][nt][1] = (unsigned)(unsigned short)f2b(p2v) | (((unsigned)(unsigned short)f2b(p3v)) << 16);
            }
        }
    }
    // GEMM-Wf: facc = hidden @ (pe_w2@at_w1)
    f32x4 facc[2][8];
#pragma unroll
    for (int mt = 0; mt < 2; mt++)
#pragma unroll
        for (int nt = 0; nt < 8; nt++) facc[mt][nt] = (f32x4){0.f, 0.f, 0.f, 0.f};
#pragma unroll
    for (int kt = 0; kt < 4; ++kt) {
        int ra = (l & 15), rb = 16 + (l & 15);
        int off = kt * 64 + (l >> 4) * 16;
        bf16x8 a0 = *(const bf16x8*)&WK[ra * 256 + (off ^ ((ra & 7) << 4))];
        bf16x8 a1 = *(const bf16x8*)&WK[rb * 256 + (off ^ ((rb & 7) << 4))];
#pragma unroll
        for (int nt = 0; nt < 8; ++nt) {
            bf16x8 bv = *(const bf16x8*)(pk_wf + (size_t)((kt * 8 + nt) * 64 + l) * 8);
            facc[0][nt] = MFMA_B16(a0, bv, facc[0][nt]);
            facc[1][nt] = MFMA_B16(a1, bv, facc[1][nt]);
        }
    }
    // wait K1 DMA + q1; relu(facc + q1 - k1) -> WK (A-layout)
    asm volatile("s_waitcnt vmcnt(0)" ::: "memory");
#pragma unroll
    for (int nt = 0; nt < 8; ++nt) {
        int col = nt * 16 + cl;
#pragma unroll
        for (int mt = 0; mt < 2; ++mt) {
            float qv = b2f((short)q1pre[mt][nt]);
#pragma unroll
            for (int j = 0; j < 4; ++j) {
                int lr = mt * 16 + (l >> 4) * 4 + j;
                float kv = b2f(*(const short*)&KV[lr * 256 + ((col * 2) ^ ((lr & 7) << 4))]);
                float x = facc[mt][nt][j] + qv - kv;
                *(short*)&WK[lr * 256 + ((col * 2) ^ ((lr & 7) << 4))] = f2b(fmaxf(x, 0.f));
            }
        }
    }
    // k1 reads retired -> V DMA into same slots (hidden under A2)
    asm volatile("s_waitcnt lgkmcnt(0)" ::: "memory");
#pragma unroll
    for (int it = 0; it < 8; ++it) {
        int g = __shfl(g_reg, it * 4 + (l >> 4));
        int srcch = cl ^ ((it * 4 + (l >> 4)) & 7);
        gload_lds16(vg + (size_t)g * 128 + srcch * 8, KV + it * 1024);
    }
    // A2 GEMM
#pragma unroll
    for (int mt = 0; mt < 2; mt++)
#pragma unroll
        for (int nt = 0; nt < 8; nt++) facc[mt][nt] = (f32x4){0.f, 0.f, 0.f, 0.f};
#pragma unroll
    for (int kt = 0; kt < 4; ++kt) {
        int ra = (l & 15), rb = 16 + (l & 15);
        int off = kt * 64 + (l >> 4) * 16;
        bf16x8 a0 = *(const bf16x8*)&WK[ra * 256 + (off ^ ((ra & 7) << 4))];
        bf16x8 a1 = *(const bf16x8*)&WK[rb * 256 + (off ^ ((rb & 7) << 4))];
#pragma unroll
        for (int nt = 0; nt < 8; ++nt) {
            bf16x8 bv = *(const bf16x8*)(pk_a2 + (size_t)((kt * 8 + nt) * 64 + l) * 8);
            facc[0][nt] = MFMA_B16(a0, bv, facc[0][nt]);
            facc[1][nt] = MFMA_B16(a1, bv, facc[1][nt]);
        }
    }
    // wait V; per-channel softmax over K + weighted (v+pe) sum
    asm volatile("s_waitcnt vmcnt(0)" ::: "memory");
    const float scale = 0.08838834764831845f;
#pragma unroll
    for (int mt = 0; mt < 2; ++mt) {
        int P = p0 + w * 2 + mt;
#pragma unroll
        for (int nt = 0; nt < 8; ++nt) {
            int col = nt * 16 + cl;
            float bv = at_b2[col];
            float vv[4];
#pragma unroll
            for (int j = 0; j < 4; ++j) vv[j] = (facc[mt][nt][j] + bv) * scale;
            float m = fmaxf(fmaxf(vv[0], vv[1]), fmaxf(vv[2], vv[3]));
            m = fmaxf(m, __shfl_xor(m, 16));
            m = fmaxf(m, __shfl_xor(m, 32));
            float ee[4], es = 0.f;
#pragma unroll
            for (int j = 0; j < 4; ++j) { ee[j] = __expf(vv[j] - m); es += ee[j]; }
            es += __shfl_xor(es, 16);
            es += __shfl_xor(es, 32);
            float pev[4];
            pev[0] = b2f((short)(pe_pk[mt][nt][0] & 0xffff));
            pev[1] = b2f((short)(pe_pk[mt][nt][0] >> 16));
            pev[2] = b2f((short)(pe_pk[mt][nt][1] & 0xffff));
            pev[3] = b2f((short)(pe_pk[mt][nt][1] >> 16));
            float o = 0.f;
#pragma unroll
            for (int j = 0; j < 4; ++j) {
                int lr = mt * 16 + (l >> 4) * 4 + j;
                float vvv = b2f(*(const short*)&KV[lr * 256 + ((col * 2) ^ ((lr & 7) << 4))]);
                o += ee[j] * (vvv + pev[j]);
            }
            o += __shfl_xor(o, 16);
            o += __shfl_xor(o, 32);
            if (l < 16) res1[(size_t)P * 128 + col] = o / es;
        }
    }
}

// ---------------- final head (f32 VALU) ----------------
__global__ __launch_bounds__(256) void k_head(const float* __restrict__ res1, const float* __restrict__ feat,
                                              const float* __restrict__ ag_w, const float* __restrict__ ag_b,
                                              const float* __restrict__ mlp_w1, const float* __restrict__ mlp_b1,
                                              const float* __restrict__ mlp_w2, const float* __restrict__ mlp_b2,
                                              float* __restrict__ out) {
    __shared__ __align__(16) float rs[64][128];
    __shared__ __align__(16) float r1s[64][64];
    int tid = threadIdx.x;
    int i0 = blockIdx.x * 64;
    for (int e = tid; e < 64 * 128; e += 256) rs[e >> 7][e & 127] = res1[(size_t)i0 * 128 + e];
    __syncthreads();
    {
        int d = tid & 63, rg = tid >> 6;
        float acc[16];
#pragma unroll
        for (int i = 0; i < 16; i++) acc[i] = 0.0f;
        for (int c4 = 0; c4 < 32; ++c4) {
            int c = c4 * 4;
            float w0 = ag_w[c * 64 + d], w1 = ag_w[(c + 1) * 64 + d];
            float w2 = ag_w[(c + 2) * 64 + d], w3 = ag_w[(c + 3) * 64 + d];
#pragma unroll
            for (int i = 0; i < 16; i++) {
                float4 f = *(const float4*)&rs[rg * 16 + i][c];
                acc[i] += f.x * w0 + f.y * w1 + f.z * w2 + f.w * w3;
            }
        }
        float bb = ag_b[d];
#pragma unroll
        for (int i = 0; i < 16; i++) {
            int pp = rg * 16 + i;
            r1s[pp][d] = acc[i] + bb + feat[(size_t)(i0 + pp) * 64 + d];
        }
    }
    __syncthreads();
    {
        int d = tid & 127, rg = tid >> 7;
        float acc[32];
#pragma unroll
        for (int i = 0; i < 32; i++) acc[i] = 0.0f;
        for (int c4 = 0; c4 < 16; ++c4) {
            int c = c4 * 4;
            float w0 = mlp_w1[c * 128 + d], w1 = mlp_w1[(c + 1) * 128 + d];
            float w2 = mlp_w1[(c + 2) * 128 + d], w3 = mlp_w1[(c + 3) * 128 + d];
#pragma unroll
            for (int i = 0; i < 32; i++) {
                float4 f = *(const float4*)&r1s[rg * 32 + i][c];
                acc[i] += f.x * w0 + f.y * w1 + f.z * w2 + f.w * w3;
            }
        }
        float bb = mlp_b1[d];
#pragma unroll
        for (int i = 0; i < 32; i++) {
            float x = acc[i] + bb;
            rs[rg * 32 + i][d] = 0.5f * x * (1.0f + erff(x * 0.70710678118654752f));
        }
    }
    __syncthreads();
    {
        int d = tid & 63, rg = tid >> 6;
        float acc[16];
#pragma unroll
        for (int i = 0; i < 16; i++) acc[i] = 0.0f;
        for (int c4 = 0; c4 < 32; ++c4) {
            int c = c4 * 4;
            float w0 = mlp_w2[c * 64 + d], w1 = mlp_w2[(c + 1) * 64 + d];
            float w2 = mlp_w2[(c + 2) * 64 + d], w3 = mlp_w2[(c + 3) * 64 + d];
#pragma unroll
            for (int i = 0; i < 16; i++) {
                float4 f = *(const float4*)&rs[rg * 16 + i][c];
                acc[i] += f.x * w0 + f.y * w1 + f.z * w2 + f.w * w3;
            }
        }
        float bb = mlp_b2[d];
#pragma unroll
        for (int i = 0; i < 16; i++) {
            int pp = rg * 16 + i;
            out[(size_t)(i0 + pp) * 64 + d] = acc[i] + bb + feat[(size_t)(i0 + pp) * 64 + d];
        }
    }
}

extern "C" void kernel_launch(void* const* d_in, const int* in_sizes, int n_in,
                              void* d_out, int out_size, void* d_ws, size_t ws_size,
                              hipStream_t stream) {
    const float* xyzp = (const float*)d_in[0];
    const float* features = (const float*)d_in[1];
    const float* ln_g = (const float*)d_in[2];
    const float* ln_b = (const float*)d_in[3];
    const float* W1 = (const float*)d_in[4];
    const float* b1 = (const float*)d_in[5];
    const float* W2 = (const float*)d_in[6];
    const float* pe_w1 = (const float*)d_in[7];
    const float* pe_b1 = (const float*)d_in[8];
    const float* pe_w2 = (const float*)d_in[9];
    const float* pe_b2 = (const float*)d_in[10];
    const float* at_w1 = (const float*)d_in[11];
    const float* at_b1 = (const float*)d_in[12];
    const float* at_w2 = (const float*)d_in[13];
    const float* at_b2 = (const float*)d_in[14];
    const float* ag_w = (const float*)d_in[15];
    const float* ag_b = (const float*)d_in[16];
    const float* mlp_w1 = (const float*)d_in[17];
    const float* mlp_b1 = (const float*)d_in[18];
    const float* mlp_w2 = (const float*)d_in[19];
    const float* mlp_b2 = (const float*)d_in[20];
    float* out = (float*)d_out;

    char* w = (char*)d_ws;
    auto alloc = [&](size_t bytes) { char* pp = w; w += (bytes + 255) & ~(size_t)255; return pp; };
    int* grid = (int*)alloc((size_t)BB * GS * GS * 4);
    short* zero256 = (short*)alloc(256);
    int* cxy = (int*)alloc((size_t)BB * NN * 4);
    unsigned* part = (unsigned*)alloc((size_t)BB * NN * NC * KNN * 4);  // reused as q1/k1 after merge
    int* idxb = (int*)alloc((size_t)BB * NN * KNN * 4);
    float4* relg = (float4*)alloc((size_t)BB * NN * KNN * 16);
    short* sp_bf = (short*)alloc((size_t)BB * NN * 128 * 2);
    short* h1_bf = (short*)alloc((size_t)BB * NN * HID * 2);
    short* qg = (short*)alloc((size_t)BB * NN * HID * 2);
    short* kg = (short*)alloc((size_t)BB * NN * HID * 2);
    short* vg = (short*)alloc((size_t)BB * NN * HID * 2);
    float* res1 = (float*)alloc((size_t)BB * NN * HID * 4);
    short* pk_pe2 = (short*)alloc((size_t)PK128_SZ * 2);
    short* pk_a1 = (short*)alloc((size_t)PK128_SZ * 2);
    short* pk_a2 = (short*)alloc((size_t)PK128_SZ * 2);
    short* pk_wf = (short*)alloc((size_t)PK128_SZ * 2);
    short* pk_w1 = (short*)alloc((size_t)PKW1_SZ * 2);
    short* pk_w2 = (short*)alloc((size_t)PKW2_SZ * 2);
    float* cf = (float*)alloc(128 * 4);
    short* q1 = (short*)part;                       // 4 MB
    short* k1 = (short*)part + (size_t)BB * NN * HID;  // 4 MB (part is 8 MB)

    k_grid_init<<<(BB * GS * GS + 128 + 255) / 256, 256, 0, stream>>>(grid, zero256);
    k_scatter<<<(BB * NN + 255) / 256, 256, 0, stream>>>(xyzp, grid, cxy);
    k_pack<<<(3 * PK128_SZ + PKW1_SZ + PKW2_SZ + 255) / 256, 256, 0, stream>>>(
        pe_w2, at_w1, at_w2, W1, W2, pk_pe2, pk_a1, pk_a2, pk_w1, pk_w2);
    k_fold<<<65, 256, 0, stream>>>(pe_w2, at_w1, pe_b2, at_b1, pk_wf, cf);
    k_knn_part<<<BB * (NN / 256) * NC, 256, 0, stream>>>(cxy, part);
    k_knn_merge<<<BB * NN / 256, 256, 0, stream>>>(part, idxb);
    k_prep<<<(BB * NN * KNN + 255) / 256, 256, 0, stream>>>(xyzp, idxb, relg);
    k_sp<<<(BB * NN + 255) / 256, 256, 0, stream>>>(xyzp, features, ln_g, ln_b, sp_bf);
    k_conv1<<<BB * NN / 64, 256, 0, stream>>>(grid, cxy, sp_bf, b1, pk_w1, zero256, h1_bf);
    k_conv2<<<(BB * NN / 64) * 3, 256, 0, stream>>>(grid, cxy, h1_bf, pk_w2, zero256, qg, kg, vg);
    k_qk1<<<512, 256, 0, stream>>>(qg, kg, pk_a1, cf, q1, k1);
    k_attn<<<BB * NN / 8, 256, 0, stream>>>(relg, q1, k1, vg, pe_w1, pe_b1, pe_b2, at_b2,
                                            pk_pe2, pk_wf, pk_a2, res1);
    k_head<<<BB * NN / 64, 256, 0, stream>>>(res1, features, ag_w, ag_b, mlp_w1, mlp_b1, mlp_w2, mlp_b2, out);
}